// Round 1
// baseline (1453.238 us; speedup 1.0000x reference)
//
#include <hip/hip_runtime.h>
#include <math.h>

// ---------- types / helpers ----------
typedef __attribute__((ext_vector_type(8))) short s16x8;
typedef __attribute__((ext_vector_type(4))) float f32x4;

__device__ __forceinline__ float bf2f(unsigned short u) {
    union { unsigned int i; float f; } c; c.i = ((unsigned int)u) << 16; return c.f;
}
__device__ __forceinline__ unsigned short f2bf(float f) {
    union { float f; unsigned int i; } c; c.f = f;
    unsigned int r = c.i + 0x7fffu + ((c.i >> 16) & 1u);
    return (unsigned short)(r >> 16);
}
__device__ __forceinline__ float wave_sum(float v) {
#pragma unroll
    for (int o = 32; o; o >>= 1) v += __shfl_xor(v, o, 64);
    return v;
}
__device__ __forceinline__ float wave_max(float v) {
#pragma unroll
    for (int o = 32; o; o >>= 1) v = fmaxf(v, __shfl_xor(v, o, 64));
    return v;
}
__device__ __forceinline__ void async_load16(const void* g, void* l) {
    __builtin_amdgcn_global_load_lds(
        (const __attribute__((address_space(1))) unsigned int*)g,
        (__attribute__((address_space(3))) unsigned int*)l, 16, 0, 0);
}

// ---------- bf16 GEMM: C[M,N] = A[M,K] * BT[N,K]^T, 128x128 tile ----------
enum { EP_BF16 = 0, EP_ADDF32 = 1, EP_BIAS_ELU_BF16 = 2, EP_BIAS_ADD_F32 = 3 };

template <int EP>
__global__ __launch_bounds__(256, 2) void gemm_bt(
    const unsigned short* __restrict__ A, int lda,
    const unsigned short* __restrict__ BT, int ldb,
    int K, int ldc,
    float* Cf, unsigned short* Cb,
    const float* __restrict__ bias, const float* addsrc)
{
    __shared__ __align__(16) unsigned short sA[128 * 32];
    __shared__ __align__(16) unsigned short sB[128 * 32];
    const int tid = threadIdx.x;
    const int w = tid >> 6, l = tid & 63;
    const int wm = w & 1, wn = w >> 1;
    const int rowBase = blockIdx.y * 128, colBase = blockIdx.x * 128;

    f32x4 acc[4][4] = {};

    const int sr = w * 32 + (l >> 2);
    const int sc = (l & 3) * 8;
    const unsigned short* gA0 = A + (size_t)(rowBase + sr) * lda + sc;
    const unsigned short* gA1 = gA0 + (size_t)16 * lda;
    const unsigned short* gB0 = BT + (size_t)(colBase + sr) * ldb + sc;
    const unsigned short* gB1 = gB0 + (size_t)16 * ldb;
    unsigned short* lA0 = sA + (w * 32) * 32;
    unsigned short* lA1 = sA + (w * 32 + 16) * 32;
    unsigned short* lB0 = sB + (w * 32) * 32;
    unsigned short* lB1 = sB + (w * 32 + 16) * 32;

    const int lm = l & 15, lq = l >> 4;
    const int aoff = (wm * 64 + lm) * 32 + lq * 8;
    const int boff = (wn * 64 + lm) * 32 + lq * 8;

    for (int k0 = 0; k0 < K; k0 += 32) {
        __syncthreads();
        async_load16(gA0 + k0, lA0);
        async_load16(gA1 + k0, lA1);
        async_load16(gB0 + k0, lB0);
        async_load16(gB1 + k0, lB1);
        __syncthreads();
        s16x8 af[4], bfr[4];
#pragma unroll
        for (int mi = 0; mi < 4; ++mi) af[mi] = *(const s16x8*)(sA + aoff + mi * 512);
#pragma unroll
        for (int ni = 0; ni < 4; ++ni) bfr[ni] = *(const s16x8*)(sB + boff + ni * 512);
#pragma unroll
        for (int mi = 0; mi < 4; ++mi)
#pragma unroll
            for (int ni = 0; ni < 4; ++ni)
                acc[mi][ni] = __builtin_amdgcn_mfma_f32_16x16x32_bf16(
                    af[mi], bfr[ni], acc[mi][ni], 0, 0, 0);
    }

#pragma unroll
    for (int mi = 0; mi < 4; ++mi) {
        const int r0 = rowBase + wm * 64 + mi * 16 + lq * 4;
#pragma unroll
        for (int ni = 0; ni < 4; ++ni) {
            const int c = colBase + wn * 64 + ni * 16 + lm;
            float bv = 0.f;
            if (EP == EP_BIAS_ELU_BF16 || EP == EP_BIAS_ADD_F32) bv = bias[c];
#pragma unroll
            for (int r = 0; r < 4; ++r) {
                const size_t idx = (size_t)(r0 + r) * ldc + c;
                float v = acc[mi][ni][r] + bv;
                if (EP == EP_ADDF32 || EP == EP_BIAS_ADD_F32) v += addsrc[idx];
                if (EP == EP_BIAS_ELU_BF16) v = v > 0.f ? v : (expf(v) - 1.f);
                if (EP == EP_BF16 || EP == EP_BIAS_ELU_BF16) Cb[idx] = f2bf(v);
                else Cf[idx] = v;
            }
        }
    }
}

// ---------- weight transpose + f32->bf16 ----------
__global__ __launch_bounds__(256) void transpose_cvt(const float* in, unsigned short* out,
                                                     int R, int C) {
    __shared__ float t[32][33];
    const int c0 = blockIdx.x * 32, r0 = blockIdx.y * 32;
    const int tx = threadIdx.x, ty = threadIdx.y;
#pragma unroll
    for (int j = 0; j < 4; ++j)
        t[ty + j * 8][tx] = in[(size_t)(r0 + ty + j * 8) * C + c0 + tx];
    __syncthreads();
#pragma unroll
    for (int j = 0; j < 4; ++j) {
        int cc = ty + j * 8;
        out[(size_t)(c0 + cc) * R + r0 + tx] = f2bf(t[tx][cc]);
    }
}

__global__ __launch_bounds__(256) void cvt_bf16(const float4* in, ushort4* out) {
    size_t i = (size_t)blockIdx.x * 256 + threadIdx.x;
    float4 v = in[i];
    ushort4 o; o.x = f2bf(v.x); o.y = f2bf(v.y); o.z = f2bf(v.z); o.w = f2bf(v.w);
    out[i] = o;
}

// ---------- FAVOR+ features ----------
// per token block: q-features (complete) + k data_dash pass1 (+diag, blockmax)
__global__ __launch_bounds__(256) void feat_qk(const unsigned short* __restrict__ qkvb,
                                               const float* __restrict__ proj,
                                               unsigned short* qf, float* kdash,
                                               float* diagk, float* bmax) {
    __shared__ float sproj[64 * 65];
    __shared__ float sq[4][64];
    __shared__ float swmax[4];
    const int t = blockIdx.x, tid = threadIdx.x;
    const int w = tid >> 6, l = tid & 63;
    for (int i = tid; i < 4096; i += 256) { int m = i >> 6, d = i & 63; sproj[m * 65 + d] = proj[i]; }
    __syncthreads();
    const float dn = 0.35355339059327373f;      // 64^-0.25
    const size_t base = (size_t)t * 3072;
    float wmax = -3.0e38f;
    for (int hh = 0; hh < 4; ++hh) {
        const int h = hh * 4 + w;
        // ---- Q features ----
        float qv = bf2f(qkvb[base + h * 64 + l]);
        float sumsq = wave_sum(qv * qv);
        sq[w][l] = qv * dn;
        __syncthreads();
        float dd = 0.f;
#pragma unroll
        for (int d = 0; d < 64; ++d) dd += sq[w][d] * sproj[l * 65 + d];
        float diag = sumsq * 0.0625f;           // * dn^2/2
        float mxq = wave_max(dd);
        qf[(size_t)t * 1024 + h * 64 + l] = f2bf(0.125f * (expf(dd - diag - mxq) + 1e-6f));
        __syncthreads();
        // ---- K data_dash ----
        float kvv = bf2f(qkvb[base + 1024 + h * 64 + l]);
        float ksq = wave_sum(kvv * kvv);
        sq[w][l] = kvv * dn;
        __syncthreads();
        float kdd = 0.f;
#pragma unroll
        for (int d = 0; d < 64; ++d) kdd += sq[w][d] * sproj[l * 65 + d];
        kdash[(size_t)t * 1024 + h * 64 + l] = kdd;
        if (l == 0) diagk[t * 16 + h] = ksq * 0.0625f;
        wmax = fmaxf(wmax, wave_max(kdd));
        __syncthreads();
    }
    if (l == 0) swmax[w] = wmax;
    __syncthreads();
    if (tid == 0) bmax[t] = fmaxf(fmaxf(swmax[0], swmax[1]), fmaxf(swmax[2], swmax[3]));
}

__global__ __launch_bounds__(256) void max_reduce(const float* bm, float* mx) {
    const int tid = threadIdx.x;
    float m = -3.0e38f;
    for (int i = tid; i < 16384; i += 256) m = fmaxf(m, bm[i]);
    m = wave_max(m);
    __shared__ float s[4];
    if ((tid & 63) == 0) s[tid >> 6] = m;
    __syncthreads();
    if (tid == 0) mx[0] = fmaxf(fmaxf(s[0], s[1]), fmaxf(s[2], s[3]));
}

__global__ __launch_bounds__(256) void kf_kernel(const float* __restrict__ kdash,
                                                 const float* __restrict__ diagk,
                                                 const float* __restrict__ mx,
                                                 unsigned short* kf) {
    const int t = blockIdx.x, tid = threadIdx.x;
    const float m = mx[0];
    for (int i = tid; i < 1024; i += 256) {
        int h = i >> 6;
        float v = 0.125f * (expf(kdash[(size_t)t * 1024 + i] - diagk[t * 16 + h] - m) + 1e-6f);
        kf[(size_t)t * 1024 + i] = f2bf(v);
    }
}

// kv[b,h,m,d] = sum_n kf * v ; ksum[b,h,m] = sum_n kf   (split over N, atomics)
__global__ __launch_bounds__(256) void kv_kernel(const unsigned short* __restrict__ kf,
                                                 const unsigned short* __restrict__ qkvb,
                                                 float* kv, float* ksum) {
    const int bh = blockIdx.x, b = bh >> 4, h = bh & 15;
    const int n0 = blockIdx.y * 512;
    const int tid = threadIdx.x;
    const int m = tid & 63, dg = tid >> 6;
    const int half = tid >> 7, nn_s = (tid >> 6) & 1, e = tid & 63;
    __shared__ float skf[2][64], sv[2][64];
    float acc[16];
#pragma unroll
    for (int j = 0; j < 16; ++j) acc[j] = 0.f;
    float ks = 0.f;
    for (int nb = 0; nb < 512; nb += 2) {
        const size_t tok = (size_t)(b * 4096 + n0 + nb + nn_s);
        __syncthreads();
        if (half == 0) skf[nn_s][e] = bf2f(kf[tok * 1024 + h * 64 + e]);
        else           sv[nn_s][e]  = bf2f(qkvb[tok * 3072 + 2048 + h * 64 + e]);
        __syncthreads();
#pragma unroll
        for (int nn = 0; nn < 2; ++nn) {
            float kfv = skf[nn][m];
            if (dg == 0) ks += kfv;
#pragma unroll
            for (int j = 0; j < 16; ++j) acc[j] += kfv * sv[nn][dg * 16 + j];
        }
    }
    const size_t ob = (size_t)bh * 4096 + (size_t)m * 64 + dg * 16;
#pragma unroll
    for (int j = 0; j < 16; ++j) atomicAdd(&kv[ob + j], acc[j]);
    if (dg == 0) atomicAdd(&ksum[bh * 64 + m], ks);
}

// attn[b,n,h,d] = (qf . kv) / (qf . ksum)
__global__ __launch_bounds__(256) void attn_kernel(const unsigned short* __restrict__ qf,
                                                   const float* __restrict__ kv,
                                                   const float* __restrict__ ksum,
                                                   unsigned short* attn) {
    const int bh = blockIdx.x, b = bh >> 4, h = bh & 15;
    const int nbase = blockIdx.y * 64;
    const int tid = threadIdx.x, w = tid >> 6, l = tid & 63;
    __shared__ float skv[64 * 65];
    __shared__ float sks[64];
    __shared__ float sqf[4][64];
    for (int i = tid; i < 4096; i += 256) { int m = i >> 6, d = i & 63; skv[m * 65 + d] = kv[(size_t)bh * 4096 + i]; }
    if (tid < 64) sks[tid] = ksum[bh * 64 + tid];
    __syncthreads();
    for (int it = 0; it < 16; ++it) {
        const int n = nbase + it * 4 + w;
        const size_t tok = (size_t)b * 4096 + n;
        float qv = bf2f(qf[tok * 1024 + h * 64 + l]);
        sqf[w][l] = qv;
        float den = wave_sum(qv * sks[l]);
        __syncthreads();
        float num = 0.f;
#pragma unroll
        for (int m2 = 0; m2 < 64; ++m2) num += sqf[w][m2] * skv[m2 * 65 + l];
        attn[tok * 1024 + h * 64 + l] = f2bf(num / den);
        __syncthreads();
    }
}

// ---------- LayerNorm (D=1024) ----------
__device__ __forceinline__ float block_sum256(float v, float* sbuf, int tid) {
    v = wave_sum(v);
    __syncthreads();
    if ((tid & 63) == 0) sbuf[tid >> 6] = v;
    __syncthreads();
    return sbuf[0] + sbuf[1] + sbuf[2] + sbuf[3];
}

template <int WB>
__global__ __launch_bounds__(256) void ln_kernel(const float* src, const float* g, const float* b,
                                                 float* dstf, unsigned short* dstb) {
    __shared__ float sbuf[4];
    const int t = blockIdx.x, tid = threadIdx.x;
    float4 v = ((const float4*)(src + (size_t)t * 1024))[tid];
    float mu = block_sum256(v.x + v.y + v.z + v.w, sbuf, tid) * (1.f / 1024.f);
    float dx = v.x - mu, dy = v.y - mu, dz = v.z - mu, dw = v.w - mu;
    float var = block_sum256(dx * dx + dy * dy + dz * dz + dw * dw, sbuf, tid) * (1.f / 1024.f);
    float r = rsqrtf(var + 1e-6f);
    float4 gv = ((const float4*)g)[tid];
    float4 bv = ((const float4*)b)[tid];
    float4 o;
    o.x = dx * r * gv.x + bv.x; o.y = dy * r * gv.y + bv.y;
    o.z = dz * r * gv.z + bv.z; o.w = dw * r * gv.w + bv.w;
    ((float4*)(dstf + (size_t)t * 1024))[tid] = o;
    if (WB) {
        ushort4 u; u.x = f2bf(o.x); u.y = f2bf(o.y); u.z = f2bf(o.z); u.w = f2bf(o.w);
        ((ushort4*)(dstb + (size_t)t * 1024))[tid] = u;
    }
}

// ---------- launcher ----------
extern "C" void kernel_launch(void* const* d_in, const int* in_sizes, int n_in,
                              void* d_out, int out_size, void* d_ws, size_t ws_size,
                              hipStream_t stream) {
    (void)in_sizes; (void)n_in; (void)out_size; (void)ws_size;
    const float* x    = (const float*)d_in[0];
    const float* Wq   = (const float*)d_in[1];
    const float* Wk   = (const float*)d_in[2];
    const float* Wv   = (const float*)d_in[3];
    const float* Wo   = (const float*)d_in[4];
    const float* proj = (const float*)d_in[5];
    const float* W1   = (const float*)d_in[6];
    const float* b1   = (const float*)d_in[7];
    const float* W2   = (const float*)d_in[8];
    const float* b2   = (const float*)d_in[9];
    const float* g1   = (const float*)d_in[10];
    const float* lb1  = (const float*)d_in[11];
    const float* g2   = (const float*)d_in[12];
    const float* lb2  = (const float*)d_in[13];

    char* ws = (char*)d_ws;
    size_t off = 0;
    auto alloc = [&](size_t bytes) { char* p = ws + off; off += (bytes + 255) & ~(size_t)255; return p; };
    unsigned short* WqkvT = (unsigned short*)alloc((size_t)3072 * 1024 * 2);
    unsigned short* WoT   = (unsigned short*)alloc((size_t)1024 * 1024 * 2);
    unsigned short* W1T   = (unsigned short*)alloc((size_t)4096 * 1024 * 2);
    unsigned short* W2T   = (unsigned short*)alloc((size_t)1024 * 4096 * 2);
    unsigned short* xb    = (unsigned short*)alloc((size_t)16384 * 1024 * 2);  // later: attn
    unsigned short* qkvb  = (unsigned short*)alloc((size_t)16384 * 3072 * 2);  // later: out1f + out1b
    unsigned short* qf    = (unsigned short*)alloc((size_t)16384 * 1024 * 2);  // later: h_half (with kf)
    unsigned short* kf    = (unsigned short*)alloc((size_t)16384 * 1024 * 2);
    float* kv    = (float*)alloc((size_t)64 * 64 * 64 * 4);
    float* ksum  = (float*)alloc((size_t)64 * 64 * 4);
    float* diagk = (float*)alloc((size_t)16384 * 16 * 4);
    float* bmax  = (float*)alloc((size_t)16384 * 4);
    float* mx    = (float*)alloc(256);

    unsigned short* attnb = xb;
    float* out1f = (float*)qkvb;
    unsigned short* out1b = (unsigned short*)((char*)qkvb + (size_t)16384 * 1024 * 4);
    unsigned short* hhalf = qf;                 // 64 MB: overlays qf+kf
    float* kdash = (float*)d_out;               // d_out doubles as fp32 scratch
    float* preLN = (float*)d_out;

    dim3 tb(32, 8);
    transpose_cvt<<<dim3(32, 32), tb, 0, stream>>>(Wq, WqkvT, 1024, 1024);
    transpose_cvt<<<dim3(32, 32), tb, 0, stream>>>(Wk, WqkvT + 1024 * 1024, 1024, 1024);
    transpose_cvt<<<dim3(32, 32), tb, 0, stream>>>(Wv, WqkvT + 2 * 1024 * 1024, 1024, 1024);
    transpose_cvt<<<dim3(32, 32), tb, 0, stream>>>(Wo, WoT, 1024, 1024);
    transpose_cvt<<<dim3(128, 32), tb, 0, stream>>>(W1, W1T, 1024, 4096);
    transpose_cvt<<<dim3(32, 128), tb, 0, stream>>>(W2, W2T, 4096, 1024);
    cvt_bf16<<<16384, 256, 0, stream>>>((const float4*)x, (ushort4*)xb);

    // QKV: [16384,1024] x [1024,3072] -> bf16 qkv
    gemm_bt<EP_BF16><<<dim3(24, 128), 256, 0, stream>>>(xb, 1024, WqkvT, 1024, 1024, 3072,
                                                        nullptr, qkvb, nullptr, nullptr);
    feat_qk<<<16384, 256, 0, stream>>>(qkvb, proj, qf, kdash, diagk, bmax);
    max_reduce<<<1, 256, 0, stream>>>(bmax, mx);
    kf_kernel<<<16384, 256, 0, stream>>>(kdash, diagk, mx, kf);
    hipMemsetAsync(kv, 0, (size_t)64 * 64 * 64 * 4 + (size_t)64 * 64 * 4, stream);
    kv_kernel<<<dim3(64, 8), 256, 0, stream>>>(kf, qkvb, kv, ksum);
    attn_kernel<<<dim3(64, 64), 256, 0, stream>>>(qf, kv, ksum, attnb);
    // attn @ Wo + x -> preLN1 (in d_out)
    gemm_bt<EP_ADDF32><<<dim3(8, 128), 256, 0, stream>>>(attnb, 1024, WoT, 1024, 1024, 1024,
                                                         preLN, nullptr, nullptr, x);
    ln_kernel<1><<<16384, 256, 0, stream>>>(preLN, g1, lb1, out1f, out1b);
    // FFN in two DFF halves (h_half reused)
    gemm_bt<EP_BIAS_ELU_BF16><<<dim3(16, 128), 256, 0, stream>>>(out1b, 1024, W1T, 1024, 1024, 2048,
                                                                 nullptr, hhalf, b1, nullptr);
    gemm_bt<EP_BIAS_ADD_F32><<<dim3(8, 128), 256, 0, stream>>>(hhalf, 2048, W2T, 4096, 2048, 1024,
                                                               preLN, nullptr, b2, out1f);
    gemm_bt<EP_BIAS_ELU_BF16><<<dim3(16, 128), 256, 0, stream>>>(out1b, 1024, W1T + (size_t)2048 * 1024,
                                                                 1024, 1024, 2048, nullptr, hhalf,
                                                                 b1 + 2048, nullptr);
    gemm_bt<EP_ADDF32><<<dim3(8, 128), 256, 0, stream>>>(hhalf, 2048, W2T + 2048, 4096, 2048, 1024,
                                                         preLN, nullptr, nullptr, preLN);
    ln_kernel<0><<<16384, 256, 0, stream>>>(preLN, g2, lb2, (float*)d_out, nullptr);
}

// Round 2
// 1255.245 us; speedup vs baseline: 1.1577x; 1.1577x over previous
//
#include <hip/hip_runtime.h>
#include <math.h>

// ---------- types / helpers ----------
typedef __attribute__((ext_vector_type(8))) short s16x8;
typedef __attribute__((ext_vector_type(4))) float f32x4;

__device__ __forceinline__ float bf2f(unsigned short u) {
    union { unsigned int i; float f; } c; c.i = ((unsigned int)u) << 16; return c.f;
}
__device__ __forceinline__ unsigned short f2bf(float f) {
    union { float f; unsigned int i; } c; c.f = f;
    unsigned int r = c.i + 0x7fffu + ((c.i >> 16) & 1u);
    return (unsigned short)(r >> 16);
}
__device__ __forceinline__ float wave_sum(float v) {
#pragma unroll
    for (int o = 32; o; o >>= 1) v += __shfl_xor(v, o, 64);
    return v;
}
__device__ __forceinline__ float wave_max(float v) {
#pragma unroll
    for (int o = 32; o; o >>= 1) v = fmaxf(v, __shfl_xor(v, o, 64));
    return v;
}
__device__ __forceinline__ void async_load16(const void* g, void* l) {
    __builtin_amdgcn_global_load_lds(
        (const __attribute__((address_space(1))) unsigned int*)g,
        (__attribute__((address_space(3))) unsigned int*)l, 16, 0, 0);
}

// ---------- bf16 GEMM: C[M,N] = A[M,K] * BT[N,K]^T, 128x128 tile ----------
enum { EP_BF16 = 0, EP_ADDF32 = 1, EP_BIAS_ELU_BF16 = 2, EP_BIAS_ADD_F32 = 3 };

template <int EP>
__global__ __launch_bounds__(256, 2) void gemm_bt(
    const unsigned short* __restrict__ A, int lda,
    const unsigned short* __restrict__ BT, int ldb,
    int K, int ldc,
    float* Cf, unsigned short* Cb,
    const float* __restrict__ bias, const float* addsrc)
{
    __shared__ __align__(16) unsigned short sA[128 * 32];
    __shared__ __align__(16) unsigned short sB[128 * 32];
    const int tid = threadIdx.x;
    const int w = tid >> 6, l = tid & 63;
    const int wm = w & 1, wn = w >> 1;
    const int rowBase = blockIdx.y * 128, colBase = blockIdx.x * 128;

    f32x4 acc[4][4] = {};

    const int sr = w * 32 + (l >> 2);
    const int sc = (l & 3) * 8;
    const unsigned short* gA0 = A + (size_t)(rowBase + sr) * lda + sc;
    const unsigned short* gA1 = gA0 + (size_t)16 * lda;
    const unsigned short* gB0 = BT + (size_t)(colBase + sr) * ldb + sc;
    const unsigned short* gB1 = gB0 + (size_t)16 * ldb;
    unsigned short* lA0 = sA + (w * 32) * 32;
    unsigned short* lA1 = sA + (w * 32 + 16) * 32;
    unsigned short* lB0 = sB + (w * 32) * 32;
    unsigned short* lB1 = sB + (w * 32 + 16) * 32;

    const int lm = l & 15, lq = l >> 4;
    const int aoff = (wm * 64 + lm) * 32 + lq * 8;
    const int boff = (wn * 64 + lm) * 32 + lq * 8;

    for (int k0 = 0; k0 < K; k0 += 32) {
        __syncthreads();
        async_load16(gA0 + k0, lA0);
        async_load16(gA1 + k0, lA1);
        async_load16(gB0 + k0, lB0);
        async_load16(gB1 + k0, lB1);
        __syncthreads();
        s16x8 af[4], bfr[4];
#pragma unroll
        for (int mi = 0; mi < 4; ++mi) af[mi] = *(const s16x8*)(sA + aoff + mi * 512);
#pragma unroll
        for (int ni = 0; ni < 4; ++ni) bfr[ni] = *(const s16x8*)(sB + boff + ni * 512);
#pragma unroll
        for (int mi = 0; mi < 4; ++mi)
#pragma unroll
            for (int ni = 0; ni < 4; ++ni)
                acc[mi][ni] = __builtin_amdgcn_mfma_f32_16x16x32_bf16(
                    af[mi], bfr[ni], acc[mi][ni], 0, 0, 0);
    }

#pragma unroll
    for (int mi = 0; mi < 4; ++mi) {
        const int r0 = rowBase + wm * 64 + mi * 16 + lq * 4;
#pragma unroll
        for (int ni = 0; ni < 4; ++ni) {
            const int c = colBase + wn * 64 + ni * 16 + lm;
            float bv = 0.f;
            if (EP == EP_BIAS_ELU_BF16 || EP == EP_BIAS_ADD_F32) bv = bias[c];
#pragma unroll
            for (int r = 0; r < 4; ++r) {
                const size_t idx = (size_t)(r0 + r) * ldc + c;
                float v = acc[mi][ni][r] + bv;
                if (EP == EP_ADDF32 || EP == EP_BIAS_ADD_F32) v += addsrc[idx];
                if (EP == EP_BIAS_ELU_BF16) v = v > 0.f ? v : (expf(v) - 1.f);
                if (EP == EP_BF16 || EP == EP_BIAS_ELU_BF16) Cb[idx] = f2bf(v);
                else Cf[idx] = v;
            }
        }
    }
}

// ---------- weight transpose + f32->bf16 ----------
__global__ __launch_bounds__(256) void transpose_cvt(const float* in, unsigned short* out,
                                                     int R, int C) {
    __shared__ float t[32][33];
    const int c0 = blockIdx.x * 32, r0 = blockIdx.y * 32;
    const int tx = threadIdx.x, ty = threadIdx.y;
#pragma unroll
    for (int j = 0; j < 4; ++j)
        t[ty + j * 8][tx] = in[(size_t)(r0 + ty + j * 8) * C + c0 + tx];
    __syncthreads();
#pragma unroll
    for (int j = 0; j < 4; ++j) {
        int cc = ty + j * 8;
        out[(size_t)(c0 + cc) * R + r0 + tx] = f2bf(t[tx][cc]);
    }
}

__global__ __launch_bounds__(256) void cvt_bf16(const float4* in, ushort4* out) {
    size_t i = (size_t)blockIdx.x * 256 + threadIdx.x;
    float4 v = in[i];
    ushort4 o; o.x = f2bf(v.x); o.y = f2bf(v.y); o.z = f2bf(v.z); o.w = f2bf(v.w);
    out[i] = o;
}

// ---------- FAVOR+ features via MFMA ----------
// block = 8 tokens (128 (token,head) rows); data_dash = (q*dn) @ proj^T via 16x16x32 MFMA.
// proj [M=64, DH=64] is already BT-layout. Writes qf (bf16, full feature), kdash (f32),
// diagk, per-block kmax.
__global__ __launch_bounds__(256, 2) void feat_mfma(
    const unsigned short* __restrict__ qkvb, const float* __restrict__ proj,
    unsigned short* __restrict__ qf, float* __restrict__ kdash,
    float* __restrict__ diagk, float* __restrict__ bmax)
{
    __shared__ __align__(16) unsigned short sQ[8192];  // [2 ks][128 rows][32 k]
    __shared__ __align__(16) unsigned short sK[8192];
    __shared__ __align__(16) unsigned short sP[4096];  // proj [2 ks][64 m][32 k]
    __shared__ float sdq[128], sdk[128];
    __shared__ float swm[4];
    const int tid = threadIdx.x, w = tid >> 6, l = tid & 63;
    const int t0 = blockIdx.x * 8;
    const int lm = l & 15, lq = l >> 4;
    const float dn2 = 0.125f;  // dn^2 applied post-MFMA (A is raw bf16 q; fold dn^2 into dd)

    // stage Q,K: wave w, j=0..3 -> token lt=2w+(j&1), ks=j>>1 (16 rows x 32 k per load)
#pragma unroll
    for (int j = 0; j < 4; ++j) {
        const int lt = 2 * w + (j & 1), ks = j >> 1;
        const size_t g = (size_t)(t0 + lt) * 3072 + (l >> 2) * 64 + ks * 32 + (l & 3) * 8;
        async_load16(qkvb + g, sQ + ks * 4096 + lt * 512);
        async_load16(qkvb + g + 1024, sK + ks * 4096 + lt * 512);
    }
    // stage proj -> bf16 LDS (BT layout, 32-k chunks)
    for (int i = tid; i < 4096; i += 256) {
        int m = i >> 6, d = i & 63;
        sP[(d >> 5) * 2048 + m * 32 + (d & 31)] = f2bf(proj[i]);
    }
    __syncthreads();

    // per-row sumsq -> diag (=sumsq * dn^2 / 2 = sumsq/16)
    {
        int r = tid & 127;
        const unsigned short* src = (tid < 128) ? sQ : sK;
        float s = 0.f;
#pragma unroll
        for (int ks = 0; ks < 2; ++ks) {
            const s16x8* p = (const s16x8*)(src + ks * 4096 + r * 32);
#pragma unroll
            for (int c = 0; c < 4; ++c) {
                s16x8 v = p[c];
#pragma unroll
                for (int e = 0; e < 8; ++e) { float f = bf2f((unsigned short)v[e]); s += f * f; }
            }
        }
        if (tid < 128) sdq[r] = s * 0.0625f; else sdk[r] = s * 0.0625f;
    }
    __syncthreads();

    // MFMA: wave w owns row tiles 2w, 2w+1
    s16x8 pf2[2][4];
#pragma unroll
    for (int ks = 0; ks < 2; ++ks)
#pragma unroll
        for (int ni = 0; ni < 4; ++ni)
            pf2[ks][ni] = *(const s16x8*)(sP + ks * 2048 + (ni * 16 + lm) * 32 + lq * 8);
    f32x4 qa[2][4] = {}, ka[2][4] = {};
#pragma unroll
    for (int i = 0; i < 2; ++i) {
        const int rowt = (w * 2 + i) * 16 + lm;
#pragma unroll
        for (int ks = 0; ks < 2; ++ks) {
            s16x8 aq = *(const s16x8*)(sQ + ks * 4096 + rowt * 32 + lq * 8);
            s16x8 ak = *(const s16x8*)(sK + ks * 4096 + rowt * 32 + lq * 8);
#pragma unroll
            for (int ni = 0; ni < 4; ++ni) {
                qa[i][ni] = __builtin_amdgcn_mfma_f32_16x16x32_bf16(aq, pf2[ks][ni], qa[i][ni], 0, 0, 0);
                ka[i][ni] = __builtin_amdgcn_mfma_f32_16x16x32_bf16(ak, pf2[ks][ni], ka[i][ni], 0, 0, 0);
            }
        }
    }

    // epilogue (dd needs * dn^2 since A was raw q: (q*dn)@(proj) ... we fed raw q, proj:
    // dd_true = raw_dd * dn)  -> NOTE: dn multiplies data only once: data*dn @ proj = dd.
    // We fed raw q, so scale by dn^2? No: scale by dn only.
    const float dn = 0.35355339059327373f;
    float kmax = -3.0e38f;
#pragma unroll
    for (int i = 0; i < 2; ++i) {
#pragma unroll
        for (int r = 0; r < 4; ++r) {
            const int row = (w * 2 + i) * 16 + lq * 4 + r;
            float q0 = qa[i][0][r] * dn, q1 = qa[i][1][r] * dn;
            float q2 = qa[i][2][r] * dn, q3 = qa[i][3][r] * dn;
            float mq = fmaxf(fmaxf(q0, q1), fmaxf(q2, q3));
#pragma unroll
            for (int o = 1; o < 16; o <<= 1) mq = fmaxf(mq, __shfl_xor(mq, o, 64));
            const float dg = sdq[row];
            const size_t ob = (size_t)t0 * 1024 + (size_t)row * 64 + lm;
            qf[ob]      = f2bf(0.125f * (expf(q0 - dg - mq) + 1e-6f));
            qf[ob + 16] = f2bf(0.125f * (expf(q1 - dg - mq) + 1e-6f));
            qf[ob + 32] = f2bf(0.125f * (expf(q2 - dg - mq) + 1e-6f));
            qf[ob + 48] = f2bf(0.125f * (expf(q3 - dg - mq) + 1e-6f));
#pragma unroll
            for (int ni = 0; ni < 4; ++ni) {
                float kd = ka[i][ni][r] * dn;
                kdash[ob + ni * 16] = kd;
                kmax = fmaxf(kmax, kd);
            }
        }
    }
    kmax = wave_max(kmax);
    if (l == 0) swm[w] = kmax;
    __syncthreads();
    if (tid < 128) diagk[t0 * 16 + tid] = sdk[tid];
    if (tid == 0) bmax[blockIdx.x] = fmaxf(fmaxf(swm[0], swm[1]), fmaxf(swm[2], swm[3]));
}

__global__ __launch_bounds__(256) void max_reduce(const float* bm, float* mx) {
    const int tid = threadIdx.x;
    float m = -3.0e38f;
    for (int i = tid; i < 2048; i += 256) m = fmaxf(m, bm[i]);
    m = wave_max(m);
    __shared__ float s[4];
    if ((tid & 63) == 0) s[tid >> 6] = m;
    __syncthreads();
    if (tid == 0) mx[0] = fmaxf(fmaxf(s[0], s[1]), fmaxf(s[2], s[3]));
}

__global__ __launch_bounds__(256) void kf_kernel(const float* __restrict__ kdash,
                                                 const float* __restrict__ diagk,
                                                 const float* __restrict__ mx,
                                                 unsigned short* kf) {
    const int t = blockIdx.x, tid = threadIdx.x;
    const float m = mx[0];
    for (int i = tid; i < 1024; i += 256) {
        int h = i >> 6;
        float v = 0.125f * (expf(kdash[(size_t)t * 1024 + i] - diagk[t * 16 + h] - m) + 1e-6f);
        kf[(size_t)t * 1024 + i] = f2bf(v);
    }
}

// ---------- kv accumulation: lane=m, wave=d-group, shuffle-broadcast v, no syncs ----------
__global__ __launch_bounds__(256) void kv_shfl(const unsigned short* __restrict__ kf,
                                               const unsigned short* __restrict__ qkvb,
                                               float* kv, float* ksum) {
    const int bh = blockIdx.x, b = bh >> 4, h = bh & 15;
    const int n0 = blockIdx.y * 256;
    const int tid = threadIdx.x, w = tid >> 6, l = tid & 63;
    float acc[16];
#pragma unroll
    for (int j = 0; j < 16; ++j) acc[j] = 0.f;
    float ks = 0.f;
    const size_t kfbase = (size_t)(b * 4096 + n0) * 1024 + h * 64 + l;
    const size_t vbase  = (size_t)(b * 4096 + n0) * 3072 + 2048 + h * 64 + l;
    for (int n = 0; n < 256; ++n) {
        float kfv = bf2f(kf[kfbase + (size_t)n * 1024]);
        float vv  = bf2f(qkvb[vbase + (size_t)n * 3072]);
        if (w == 0) ks += kfv;
#pragma unroll
        for (int j = 0; j < 16; ++j) acc[j] += kfv * __shfl(vv, w * 16 + j, 64);
    }
    float* kvp = kv + (size_t)bh * 4096 + (size_t)l * 64 + w * 16;
#pragma unroll
    for (int j = 0; j < 16; ++j) atomicAdd(kvp + j, acc[j]);
    if (w == 0) atomicAdd(ksum + bh * 64 + l, ks);
}

// ---------- attention combine via MFMA, den folded as output column 64 ----------
__global__ __launch_bounds__(256, 2) void attn_mfma(const unsigned short* __restrict__ qf,
                                                    const float* __restrict__ kv,
                                                    const float* __restrict__ ksum,
                                                    unsigned short* __restrict__ attn) {
    __shared__ __align__(16) unsigned short sA[8192];  // [2 ks][128 rows][32 m]
    __shared__ __align__(16) unsigned short sB[5120];  // [2 ks][80 cols][32 m]; col64=ksum
    const int tid = threadIdx.x, w = tid >> 6, l = tid & 63;
    const int bh = blockIdx.x, b = bh >> 4, h = bh & 15;
    const int n0 = blockIdx.y * 128;
    const int lm = l & 15, lq = l >> 4;

    // stage A (qf rows for this (b,h))
#pragma unroll
    for (int j = 0; j < 4; ++j) {
        const int r0 = w * 32 + (j & 1) * 16, ks = j >> 1;
        const size_t g = (size_t)(b * 4096 + n0 + r0 + (l >> 2)) * 1024 + h * 64 + ks * 32 + (l & 3) * 8;
        async_load16(qf + g, sA + ks * 4096 + r0 * 32);
    }
    for (int i = tid; i < 5120; i += 256) sB[i] = 0;
    __syncthreads();
    for (int i = tid; i < 4096; i += 256) {
        int m = i >> 6, d = i & 63;
        sB[(m >> 5) * 2560 + d * 32 + (m & 31)] = f2bf(kv[(size_t)bh * 4096 + i]);
    }
    if (tid < 64) {
        int m = tid;
        sB[(m >> 5) * 2560 + 64 * 32 + (m & 31)] = f2bf(ksum[bh * 64 + m]);
    }
    __syncthreads();

    s16x8 bf2r[2][5];
#pragma unroll
    for (int ks = 0; ks < 2; ++ks)
#pragma unroll
        for (int ni = 0; ni < 5; ++ni)
            bf2r[ks][ni] = *(const s16x8*)(sB + ks * 2560 + (ni * 16 + lm) * 32 + lq * 8);
    f32x4 acc[2][5] = {};
#pragma unroll
    for (int i = 0; i < 2; ++i) {
        const int rowt = (w * 2 + i) * 16 + lm;
#pragma unroll
        for (int ks = 0; ks < 2; ++ks) {
            s16x8 a = *(const s16x8*)(sA + ks * 4096 + rowt * 32 + lq * 8);
#pragma unroll
            for (int ni = 0; ni < 5; ++ni)
                acc[i][ni] = __builtin_amdgcn_mfma_f32_16x16x32_bf16(a, bf2r[ks][ni], acc[i][ni], 0, 0, 0);
        }
    }
#pragma unroll
    for (int i = 0; i < 2; ++i) {
#pragma unroll
        for (int r = 0; r < 4; ++r) {
            const int row = (w * 2 + i) * 16 + lq * 4 + r;
            float den = __shfl(acc[i][4][r], l & 48, 64);
            float rd = 1.f / den;
            const size_t ob = (size_t)(b * 4096 + n0 + row) * 1024 + h * 64 + lm;
            attn[ob]      = f2bf(acc[i][0][r] * rd);
            attn[ob + 16] = f2bf(acc[i][1][r] * rd);
            attn[ob + 32] = f2bf(acc[i][2][r] * rd);
            attn[ob + 48] = f2bf(acc[i][3][r] * rd);
        }
    }
}

// ---------- LayerNorm (D=1024) ----------
__device__ __forceinline__ float block_sum256(float v, float* sbuf, int tid) {
    v = wave_sum(v);
    __syncthreads();
    if ((tid & 63) == 0) sbuf[tid >> 6] = v;
    __syncthreads();
    return sbuf[0] + sbuf[1] + sbuf[2] + sbuf[3];
}

template <int WB>
__global__ __launch_bounds__(256) void ln_kernel(const float* src, const float* g, const float* b,
                                                 float* dstf, unsigned short* dstb) {
    __shared__ float sbuf[4];
    const int t = blockIdx.x, tid = threadIdx.x;
    float4 v = ((const float4*)(src + (size_t)t * 1024))[tid];
    float mu = block_sum256(v.x + v.y + v.z + v.w, sbuf, tid) * (1.f / 1024.f);
    float dx = v.x - mu, dy = v.y - mu, dz = v.z - mu, dw = v.w - mu;
    float var = block_sum256(dx * dx + dy * dy + dz * dz + dw * dw, sbuf, tid) * (1.f / 1024.f);
    float r = rsqrtf(var + 1e-6f);
    float4 gv = ((const float4*)g)[tid];
    float4 bv = ((const float4*)b)[tid];
    float4 o;
    o.x = dx * r * gv.x + bv.x; o.y = dy * r * gv.y + bv.y;
    o.z = dz * r * gv.z + bv.z; o.w = dw * r * gv.w + bv.w;
    ((float4*)(dstf + (size_t)t * 1024))[tid] = o;
    if (WB) {
        ushort4 u; u.x = f2bf(o.x); u.y = f2bf(o.y); u.z = f2bf(o.z); u.w = f2bf(o.w);
        ((ushort4*)(dstb + (size_t)t * 1024))[tid] = u;
    }
}

// ---------- launcher ----------
extern "C" void kernel_launch(void* const* d_in, const int* in_sizes, int n_in,
                              void* d_out, int out_size, void* d_ws, size_t ws_size,
                              hipStream_t stream) {
    (void)in_sizes; (void)n_in; (void)out_size; (void)ws_size;
    const float* x    = (const float*)d_in[0];
    const float* Wq   = (const float*)d_in[1];
    const float* Wk   = (const float*)d_in[2];
    const float* Wv   = (const float*)d_in[3];
    const float* Wo   = (const float*)d_in[4];
    const float* proj = (const float*)d_in[5];
    const float* W1   = (const float*)d_in[6];
    const float* b1   = (const float*)d_in[7];
    const float* W2   = (const float*)d_in[8];
    const float* b2   = (const float*)d_in[9];
    const float* g1   = (const float*)d_in[10];
    const float* lb1  = (const float*)d_in[11];
    const float* g2   = (const float*)d_in[12];
    const float* lb2  = (const float*)d_in[13];

    char* ws = (char*)d_ws;
    size_t off = 0;
    auto alloc = [&](size_t bytes) { char* p = ws + off; off += (bytes + 255) & ~(size_t)255; return p; };
    unsigned short* WqkvT = (unsigned short*)alloc((size_t)3072 * 1024 * 2);
    unsigned short* WoT   = (unsigned short*)alloc((size_t)1024 * 1024 * 2);
    unsigned short* W1T   = (unsigned short*)alloc((size_t)4096 * 1024 * 2);
    unsigned short* W2T   = (unsigned short*)alloc((size_t)1024 * 4096 * 2);
    unsigned short* xb    = (unsigned short*)alloc((size_t)16384 * 1024 * 2);  // later: attn
    unsigned short* qkvb  = (unsigned short*)alloc((size_t)16384 * 3072 * 2);  // later: out1f + out1b
    unsigned short* qf    = (unsigned short*)alloc((size_t)16384 * 1024 * 2);  // later: h_half (with kf)
    unsigned short* kf    = (unsigned short*)alloc((size_t)16384 * 1024 * 2);
    float* kv    = (float*)alloc((size_t)64 * 64 * 64 * 4);
    float* ksum  = (float*)alloc((size_t)64 * 64 * 4);
    float* diagk = (float*)alloc((size_t)16384 * 16 * 4);
    float* bmax  = (float*)alloc((size_t)16384 * 4);
    float* mx    = (float*)alloc(256);

    unsigned short* attnb = xb;
    float* out1f = (float*)qkvb;
    unsigned short* out1b = (unsigned short*)((char*)qkvb + (size_t)16384 * 1024 * 4);
    unsigned short* hhalf = qf;                 // 64 MB: overlays qf+kf
    float* kdash = (float*)d_out;               // d_out doubles as fp32 scratch
    float* preLN = (float*)d_out;

    dim3 tb(32, 8);
    transpose_cvt<<<dim3(32, 32), tb, 0, stream>>>(Wq, WqkvT, 1024, 1024);
    transpose_cvt<<<dim3(32, 32), tb, 0, stream>>>(Wk, WqkvT + 1024 * 1024, 1024, 1024);
    transpose_cvt<<<dim3(32, 32), tb, 0, stream>>>(Wv, WqkvT + 2 * 1024 * 1024, 1024, 1024);
    transpose_cvt<<<dim3(32, 32), tb, 0, stream>>>(Wo, WoT, 1024, 1024);
    transpose_cvt<<<dim3(128, 32), tb, 0, stream>>>(W1, W1T, 1024, 4096);
    transpose_cvt<<<dim3(32, 128), tb, 0, stream>>>(W2, W2T, 4096, 1024);
    cvt_bf16<<<16384, 256, 0, stream>>>((const float4*)x, (ushort4*)xb);

    // QKV: [16384,1024] x [1024,3072] -> bf16 qkv
    gemm_bt<EP_BF16><<<dim3(24, 128), 256, 0, stream>>>(xb, 1024, WqkvT, 1024, 1024, 3072,
                                                        nullptr, qkvb, nullptr, nullptr);
    feat_mfma<<<2048, 256, 0, stream>>>(qkvb, proj, qf, kdash, diagk, bmax);
    max_reduce<<<1, 256, 0, stream>>>(bmax, mx);
    kf_kernel<<<16384, 256, 0, stream>>>(kdash, diagk, mx, kf);
    hipMemsetAsync(kv, 0, (size_t)64 * 64 * 64 * 4 + (size_t)64 * 64 * 4, stream);
    kv_shfl<<<dim3(64, 16), 256, 0, stream>>>(kf, qkvb, kv, ksum);
    attn_mfma<<<dim3(64, 32), 256, 0, stream>>>(qf, kv, ksum, attnb);
    // attn @ Wo + x -> preLN1 (in d_out)
    gemm_bt<EP_ADDF32><<<dim3(8, 128), 256, 0, stream>>>(attnb, 1024, WoT, 1024, 1024, 1024,
                                                         preLN, nullptr, nullptr, x);
    ln_kernel<1><<<16384, 256, 0, stream>>>(preLN, g1, lb1, out1f, out1b);
    // FFN in two DFF halves (h_half reused)
    gemm_bt<EP_BIAS_ELU_BF16><<<dim3(16, 128), 256, 0, stream>>>(out1b, 1024, W1T, 1024, 1024, 2048,
                                                                 nullptr, hhalf, b1, nullptr);
    gemm_bt<EP_BIAS_ADD_F32><<<dim3(8, 128), 256, 0, stream>>>(hhalf, 2048, W2T, 4096, 2048, 1024,
                                                               preLN, nullptr, b2, out1f);
    gemm_bt<EP_BIAS_ELU_BF16><<<dim3(16, 128), 256, 0, stream>>>(out1b, 1024, W1T + (size_t)2048 * 1024,
                                                                 1024, 1024, 2048, nullptr, hhalf,
                                                                 b1 + 2048, nullptr);
    gemm_bt<EP_ADDF32><<<dim3(8, 128), 256, 0, stream>>>(hhalf, 2048, W2T + 2048, 4096, 2048, 1024,
                                                         preLN, nullptr, nullptr, preLN);
    ln_kernel<0><<<16384, 256, 0, stream>>>(preLN, g2, lb2, (float*)d_out, nullptr);
}

// Round 3
// 964.303 us; speedup vs baseline: 1.5070x; 1.3017x over previous
//
#include <hip/hip_runtime.h>
#include <math.h>

// ---------- types / helpers ----------
typedef __attribute__((ext_vector_type(8))) short s16x8;
typedef __attribute__((ext_vector_type(4))) float f32x4;

__device__ __forceinline__ float bf2f(unsigned short u) {
    union { unsigned int i; float f; } c; c.i = ((unsigned int)u) << 16; return c.f;
}
__device__ __forceinline__ unsigned short f2bf(float f) {
    union { float f; unsigned int i; } c; c.f = f;
    unsigned int r = c.i + 0x7fffu + ((c.i >> 16) & 1u);
    return (unsigned short)(r >> 16);
}
__device__ __forceinline__ float wave_sum(float v) {
#pragma unroll
    for (int o = 32; o; o >>= 1) v += __shfl_xor(v, o, 64);
    return v;
}
__device__ __forceinline__ float wave_max(float v) {
#pragma unroll
    for (int o = 32; o; o >>= 1) v = fmaxf(v, __shfl_xor(v, o, 64));
    return v;
}
__device__ __forceinline__ void async_load16(const void* g, void* l) {
    __builtin_amdgcn_global_load_lds(
        (const __attribute__((address_space(1))) unsigned int*)g,
        (__attribute__((address_space(3))) unsigned int*)l, 16, 0, 0);
}

// ---------- bf16 GEMM: C[M,N] = A[M,K] * BT[N,K]^T, 128x128 tile ----------
enum { EP_BF16 = 0, EP_ADDF32 = 1, EP_BIAS_ELU_BF16 = 2, EP_BIAS_ADD_F32 = 3, EP_QKV = 4 };

template <int EP>
__global__ __launch_bounds__(256, 2) void gemm_bt(
    const unsigned short* __restrict__ A, int lda,
    const unsigned short* __restrict__ BT, int ldb,
    int K, int ldc,
    float* Cf, unsigned short* Cb,
    const float* __restrict__ bias, const float* addsrc,
    unsigned short* vtout)
{
    __shared__ __align__(16) unsigned short sA[128 * 32];
    __shared__ __align__(16) unsigned short sB[128 * 32];
    const int tid = threadIdx.x;
    const int w = tid >> 6, l = tid & 63;
    const int wm = w & 1, wn = w >> 1;
    const int rowBase = blockIdx.y * 128, colBase = blockIdx.x * 128;

    f32x4 acc[4][4] = {};

    const int sr = w * 32 + (l >> 2);
    const int sc = (l & 3) * 8;
    const unsigned short* gA0 = A + (size_t)(rowBase + sr) * lda + sc;
    const unsigned short* gA1 = gA0 + (size_t)16 * lda;
    const unsigned short* gB0 = BT + (size_t)(colBase + sr) * ldb + sc;
    const unsigned short* gB1 = gB0 + (size_t)16 * ldb;
    unsigned short* lA0 = sA + (w * 32) * 32;
    unsigned short* lA1 = sA + (w * 32 + 16) * 32;
    unsigned short* lB0 = sB + (w * 32) * 32;
    unsigned short* lB1 = sB + (w * 32 + 16) * 32;

    const int lm = l & 15, lq = l >> 4;
    const int aoff = (wm * 64 + lm) * 32 + lq * 8;
    const int boff = (wn * 64 + lm) * 32 + lq * 8;

    for (int k0 = 0; k0 < K; k0 += 32) {
        __syncthreads();
        async_load16(gA0 + k0, lA0);
        async_load16(gA1 + k0, lA1);
        async_load16(gB0 + k0, lB0);
        async_load16(gB1 + k0, lB1);
        __syncthreads();
        s16x8 af[4], bfr[4];
#pragma unroll
        for (int mi = 0; mi < 4; ++mi) af[mi] = *(const s16x8*)(sA + aoff + mi * 512);
#pragma unroll
        for (int ni = 0; ni < 4; ++ni) bfr[ni] = *(const s16x8*)(sB + boff + ni * 512);
#pragma unroll
        for (int mi = 0; mi < 4; ++mi)
#pragma unroll
            for (int ni = 0; ni < 4; ++ni)
                acc[mi][ni] = __builtin_amdgcn_mfma_f32_16x16x32_bf16(
                    af[mi], bfr[ni], acc[mi][ni], 0, 0, 0);
    }

    if (EP == EP_QKV && colBase >= 2048) {
        // write V part transposed: vT[(b*16+h)*64+d][n], 4 consecutive tokens -> ushort4
#pragma unroll
        for (int mi = 0; mi < 4; ++mi) {
            const int row0 = rowBase + wm * 64 + mi * 16 + lq * 4;
            const int bb = row0 >> 12, nn = row0 & 4095;
#pragma unroll
            for (int ni = 0; ni < 4; ++ni) {
                const int c = colBase + wn * 64 + ni * 16 + lm - 2048;
                const int hv = c >> 6, dv = c & 63;
                ushort4 u;
                u.x = f2bf(acc[mi][ni][0]); u.y = f2bf(acc[mi][ni][1]);
                u.z = f2bf(acc[mi][ni][2]); u.w = f2bf(acc[mi][ni][3]);
                *(ushort4*)(vtout + ((size_t)(bb * 16 + hv) * 64 + dv) * 4096 + nn) = u;
            }
        }
    } else {
#pragma unroll
        for (int mi = 0; mi < 4; ++mi) {
            const int r0 = rowBase + wm * 64 + mi * 16 + lq * 4;
#pragma unroll
            for (int ni = 0; ni < 4; ++ni) {
                const int c = colBase + wn * 64 + ni * 16 + lm;
                float bv = 0.f;
                if (EP == EP_BIAS_ELU_BF16 || EP == EP_BIAS_ADD_F32) bv = bias[c];
#pragma unroll
                for (int r = 0; r < 4; ++r) {
                    const size_t idx = (size_t)(r0 + r) * ldc + c;
                    float v = acc[mi][ni][r] + bv;
                    if (EP == EP_ADDF32 || EP == EP_BIAS_ADD_F32) v += addsrc[idx];
                    if (EP == EP_BIAS_ELU_BF16) v = v > 0.f ? v : (expf(v) - 1.f);
                    if (EP == EP_BF16 || EP == EP_BIAS_ELU_BF16 || EP == EP_QKV) Cb[idx] = f2bf(v);
                    else Cf[idx] = v;
                }
            }
        }
    }
}

// ---------- weight transpose + f32->bf16 ----------
__global__ __launch_bounds__(256) void transpose_cvt(const float* in, unsigned short* out,
                                                     int R, int C) {
    __shared__ float t[32][33];
    const int c0 = blockIdx.x * 32, r0 = blockIdx.y * 32;
    const int tx = threadIdx.x, ty = threadIdx.y;
#pragma unroll
    for (int j = 0; j < 4; ++j)
        t[ty + j * 8][tx] = in[(size_t)(r0 + ty + j * 8) * C + c0 + tx];
    __syncthreads();
#pragma unroll
    for (int j = 0; j < 4; ++j) {
        int cc = ty + j * 8;
        out[(size_t)(c0 + cc) * R + r0 + tx] = f2bf(t[tx][cc]);
    }
}

__global__ __launch_bounds__(256) void cvt_bf16(const float4* in, ushort4* out) {
    size_t i = (size_t)blockIdx.x * 256 + threadIdx.x;
    float4 v = in[i];
    ushort4 o; o.x = f2bf(v.x); o.y = f2bf(v.y); o.z = f2bf(v.z); o.w = f2bf(v.w);
    out[i] = o;
}

// ---------- FAVOR+ features via MFMA ----------
__global__ __launch_bounds__(256, 2) void feat_mfma(
    const unsigned short* __restrict__ qkvb, const float* __restrict__ proj,
    unsigned short* __restrict__ qf, float* __restrict__ kdash,
    float* __restrict__ diagk, float* __restrict__ bmax)
{
    __shared__ __align__(16) unsigned short sQ[8192];  // [2 ks][128 rows][32 k]
    __shared__ __align__(16) unsigned short sK[8192];
    __shared__ __align__(16) unsigned short sP[4096];  // proj [2 ks][64 m][32 k]
    __shared__ float sdq[128], sdk[128];
    __shared__ float swm[4];
    const int tid = threadIdx.x, w = tid >> 6, l = tid & 63;
    const int t0 = blockIdx.x * 8;
    const int lm = l & 15, lq = l >> 4;

#pragma unroll
    for (int j = 0; j < 4; ++j) {
        const int lt = 2 * w + (j & 1), ks = j >> 1;
        const size_t g = (size_t)(t0 + lt) * 3072 + (l >> 2) * 64 + ks * 32 + (l & 3) * 8;
        async_load16(qkvb + g, sQ + ks * 4096 + lt * 512);
        async_load16(qkvb + g + 1024, sK + ks * 4096 + lt * 512);
    }
    for (int i = tid; i < 4096; i += 256) {
        int m = i >> 6, d = i & 63;
        sP[(d >> 5) * 2048 + m * 32 + (d & 31)] = f2bf(proj[i]);
    }
    __syncthreads();

    {
        int r = tid & 127;
        const unsigned short* src = (tid < 128) ? sQ : sK;
        float s = 0.f;
#pragma unroll
        for (int ks = 0; ks < 2; ++ks) {
            const s16x8* p = (const s16x8*)(src + ks * 4096 + r * 32);
#pragma unroll
            for (int c = 0; c < 4; ++c) {
                s16x8 v = p[c];
#pragma unroll
                for (int e = 0; e < 8; ++e) { float f = bf2f((unsigned short)v[e]); s += f * f; }
            }
        }
        if (tid < 128) sdq[r] = s * 0.0625f; else sdk[r] = s * 0.0625f;
    }
    __syncthreads();

    s16x8 pf2[2][4];
#pragma unroll
    for (int ks = 0; ks < 2; ++ks)
#pragma unroll
        for (int ni = 0; ni < 4; ++ni)
            pf2[ks][ni] = *(const s16x8*)(sP + ks * 2048 + (ni * 16 + lm) * 32 + lq * 8);
    f32x4 qa[2][4] = {}, ka[2][4] = {};
#pragma unroll
    for (int i = 0; i < 2; ++i) {
        const int rowt = (w * 2 + i) * 16 + lm;
#pragma unroll
        for (int ks = 0; ks < 2; ++ks) {
            s16x8 aq = *(const s16x8*)(sQ + ks * 4096 + rowt * 32 + lq * 8);
            s16x8 ak = *(const s16x8*)(sK + ks * 4096 + rowt * 32 + lq * 8);
#pragma unroll
            for (int ni = 0; ni < 4; ++ni) {
                qa[i][ni] = __builtin_amdgcn_mfma_f32_16x16x32_bf16(aq, pf2[ks][ni], qa[i][ni], 0, 0, 0);
                ka[i][ni] = __builtin_amdgcn_mfma_f32_16x16x32_bf16(ak, pf2[ks][ni], ka[i][ni], 0, 0, 0);
            }
        }
    }

    const float dn = 0.35355339059327373f;
    float kmax = -3.0e38f;
#pragma unroll
    for (int i = 0; i < 2; ++i) {
#pragma unroll
        for (int r = 0; r < 4; ++r) {
            const int row = (w * 2 + i) * 16 + lq * 4 + r;
            float q0 = qa[i][0][r] * dn, q1 = qa[i][1][r] * dn;
            float q2 = qa[i][2][r] * dn, q3 = qa[i][3][r] * dn;
            float mq = fmaxf(fmaxf(q0, q1), fmaxf(q2, q3));
#pragma unroll
            for (int o = 1; o < 16; o <<= 1) mq = fmaxf(mq, __shfl_xor(mq, o, 64));
            const float dg = sdq[row];
            const size_t ob = (size_t)t0 * 1024 + (size_t)row * 64 + lm;
            qf[ob]      = f2bf(0.125f * (expf(q0 - dg - mq) + 1e-6f));
            qf[ob + 16] = f2bf(0.125f * (expf(q1 - dg - mq) + 1e-6f));
            qf[ob + 32] = f2bf(0.125f * (expf(q2 - dg - mq) + 1e-6f));
            qf[ob + 48] = f2bf(0.125f * (expf(q3 - dg - mq) + 1e-6f));
#pragma unroll
            for (int ni = 0; ni < 4; ++ni) {
                float kd = ka[i][ni][r] * dn;
                kdash[ob + ni * 16] = kd;
                kmax = fmaxf(kmax, kd);
            }
        }
    }
    kmax = wave_max(kmax);
    if (l == 0) swm[w] = kmax;
    __syncthreads();
    if (tid < 128) diagk[t0 * 16 + tid] = sdk[tid];
    if (tid == 0) bmax[blockIdx.x] = fmaxf(fmaxf(swm[0], swm[1]), fmaxf(swm[2], swm[3]));
}

__global__ __launch_bounds__(256) void max_reduce(const float* bm, float* mx) {
    const int tid = threadIdx.x;
    float m = -3.0e38f;
    for (int i = tid; i < 2048; i += 256) m = fmaxf(m, bm[i]);
    m = wave_max(m);
    __shared__ float s[4];
    if ((tid & 63) == 0) s[tid >> 6] = m;
    __syncthreads();
    if (tid == 0) mx[0] = fmaxf(fmaxf(s[0], s[1]), fmaxf(s[2], s[3]));
}

// ---------- fused kf + kv/ksum via MFMA ----------
// kv[bh][m][d] = sum_n kf[n,m] * v[n,d]; ksum via ones-column tile.
// kf computed on the fly from kdash (exp), transposed into LDS; v staged from vT.
__global__ __launch_bounds__(256, 2) void kv_fused(
    const float* __restrict__ kdash, const float* __restrict__ diagk,
    const float* __restrict__ mx, const unsigned short* __restrict__ vT,
    float* kv, float* ksum)
{
    __shared__ __align__(16) unsigned short sKF[64 * 72];
    __shared__ __align__(16) unsigned short sV[64 * 72];
    __shared__ float sDiag[1024];
    const int tid = threadIdx.x, w = tid >> 6, l = tid & 63;
    const int bh = blockIdx.x, b = bh >> 4, h = bh & 15;
    const int n0 = blockIdx.y * 1024;
    const int lm = l & 15, lq = l >> 4;
    const float mxv = mx[0];

    for (int i = tid; i < 1024; i += 256)
        sDiag[i] = diagk[(size_t)(b * 4096 + n0 + i) * 16 + h] + mxv;

    s16x8 onesf;
    {
        short ov = (lm == 0) ? (short)0x3F80 : (short)0;
#pragma unroll
        for (int j = 0; j < 8; ++j) onesf[j] = ov;
    }
    f32x4 acc[4] = {};
    f32x4 accS = {};
    __syncthreads();

    for (int c0 = 0; c0 < 1024; c0 += 64) {
        __syncthreads();
        // kf staging: lane l = token, wave w = m-strip (writes its own strip)
        {
            const int n = c0 + l;
            const size_t krow = ((size_t)(b * 4096 + n0 + n)) * 1024 + h * 64 + w * 16;
            const float4* kp = (const float4*)(kdash + krow);
            float4 k0 = kp[0], k1 = kp[1], k2 = kp[2], k3 = kp[3];
            const float dg = sDiag[n];
            float vv[16] = {k0.x, k0.y, k0.z, k0.w, k1.x, k1.y, k1.z, k1.w,
                            k2.x, k2.y, k2.z, k2.w, k3.x, k3.y, k3.z, k3.w};
            unsigned short* dst = sKF + (w * 16) * 72 + l;
#pragma unroll
            for (int e = 0; e < 16; ++e)
                dst[e * 72] = f2bf(0.125f * (expf(vv[e] - dg) + 1e-6f));
        }
        // v staging: thread d = tid>>2, nq = tid&3 (vector b128 writes)
        {
            const int d = tid >> 2, nq = tid & 3;
            const uint4* vp = (const uint4*)(vT + ((size_t)bh * 64 + d) * 4096 + n0 + c0 + nq * 16);
            uint4 v0 = vp[0], v1 = vp[1];
            uint4* ldst = (uint4*)(sV + d * 72 + nq * 16);
            ldst[0] = v0; ldst[1] = v1;
        }
        __syncthreads();
#pragma unroll
        for (int ks = 0; ks < 2; ++ks) {
            s16x8 a = *(const s16x8*)(sKF + (w * 16 + lm) * 72 + ks * 32 + lq * 8);
            accS = __builtin_amdgcn_mfma_f32_16x16x32_bf16(a, onesf, accS, 0, 0, 0);
#pragma unroll
            for (int ni = 0; ni < 4; ++ni) {
                s16x8 bf = *(const s16x8*)(sV + (ni * 16 + lm) * 72 + ks * 32 + lq * 8);
                acc[ni] = __builtin_amdgcn_mfma_f32_16x16x32_bf16(a, bf, acc[ni], 0, 0, 0);
            }
        }
    }

    const size_t kvbase = (size_t)bh * 4096;
#pragma unroll
    for (int ni = 0; ni < 4; ++ni)
#pragma unroll
        for (int r = 0; r < 4; ++r)
            atomicAdd(kv + kvbase + (size_t)(w * 16 + lq * 4 + r) * 64 + ni * 16 + lm, acc[ni][r]);
    if (lm == 0)
#pragma unroll
        for (int r = 0; r < 4; ++r)
            atomicAdd(ksum + bh * 64 + w * 16 + lq * 4 + r, accS[r]);
}

// ---------- attention combine via MFMA, den folded as output column 64 ----------
__global__ __launch_bounds__(256, 2) void attn_mfma(const unsigned short* __restrict__ qf,
                                                    const float* __restrict__ kv,
                                                    const float* __restrict__ ksum,
                                                    unsigned short* __restrict__ attn) {
    __shared__ __align__(16) unsigned short sA[8192];  // [2 ks][128 rows][32 m]
    __shared__ __align__(16) unsigned short sB[5120];  // [2 ks][80 cols][32 m]; col64=ksum
    const int tid = threadIdx.x, w = tid >> 6, l = tid & 63;
    const int bh = blockIdx.x, b = bh >> 4, h = bh & 15;
    const int n0 = blockIdx.y * 128;
    const int lm = l & 15, lq = l >> 4;

#pragma unroll
    for (int j = 0; j < 4; ++j) {
        const int r0 = w * 32 + (j & 1) * 16, ks = j >> 1;
        const size_t g = (size_t)(b * 4096 + n0 + r0 + (l >> 2)) * 1024 + h * 64 + ks * 32 + (l & 3) * 8;
        async_load16(qf + g, sA + ks * 4096 + r0 * 32);
    }
    for (int i = tid; i < 5120; i += 256) sB[i] = 0;
    __syncthreads();
    for (int i = tid; i < 4096; i += 256) {
        int m = i >> 6, d = i & 63;
        sB[(m >> 5) * 2560 + d * 32 + (m & 31)] = f2bf(kv[(size_t)bh * 4096 + i]);
    }
    if (tid < 64) {
        int m = tid;
        sB[(m >> 5) * 2560 + 64 * 32 + (m & 31)] = f2bf(ksum[bh * 64 + m]);
    }
    __syncthreads();

    s16x8 bf2r[2][5];
#pragma unroll
    for (int ks = 0; ks < 2; ++ks)
#pragma unroll
        for (int ni = 0; ni < 5; ++ni)
            bf2r[ks][ni] = *(const s16x8*)(sB + ks * 2560 + (ni * 16 + lm) * 32 + lq * 8);
    f32x4 acc[2][5] = {};
#pragma unroll
    for (int i = 0; i < 2; ++i) {
        const int rowt = (w * 2 + i) * 16 + lm;
#pragma unroll
        for (int ks = 0; ks < 2; ++ks) {
            s16x8 a = *(const s16x8*)(sA + ks * 4096 + rowt * 32 + lq * 8);
#pragma unroll
            for (int ni = 0; ni < 5; ++ni)
                acc[i][ni] = __builtin_amdgcn_mfma_f32_16x16x32_bf16(a, bf2r[ks][ni], acc[i][ni], 0, 0, 0);
        }
    }
#pragma unroll
    for (int i = 0; i < 2; ++i) {
#pragma unroll
        for (int r = 0; r < 4; ++r) {
            const int row = (w * 2 + i) * 16 + lq * 4 + r;
            float den = __shfl(acc[i][4][r], l & 48, 64);
            float rd = 1.f / den;
            const size_t ob = (size_t)(b * 4096 + n0 + row) * 1024 + h * 64 + lm;
            attn[ob]      = f2bf(acc[i][0][r] * rd);
            attn[ob + 16] = f2bf(acc[i][1][r] * rd);
            attn[ob + 32] = f2bf(acc[i][2][r] * rd);
            attn[ob + 48] = f2bf(acc[i][3][r] * rd);
        }
    }
}

// ---------- LayerNorm (D=1024) ----------
__device__ __forceinline__ float block_sum256(float v, float* sbuf, int tid) {
    v = wave_sum(v);
    __syncthreads();
    if ((tid & 63) == 0) sbuf[tid >> 6] = v;
    __syncthreads();
    return sbuf[0] + sbuf[1] + sbuf[2] + sbuf[3];
}

template <int WB>
__global__ __launch_bounds__(256) void ln_kernel(const float* src, const float* g, const float* b,
                                                 float* dstf, unsigned short* dstb) {
    __shared__ float sbuf[4];
    const int t = blockIdx.x, tid = threadIdx.x;
    float4 v = ((const float4*)(src + (size_t)t * 1024))[tid];
    float mu = block_sum256(v.x + v.y + v.z + v.w, sbuf, tid) * (1.f / 1024.f);
    float dx = v.x - mu, dy = v.y - mu, dz = v.z - mu, dw = v.w - mu;
    float var = block_sum256(dx * dx + dy * dy + dz * dz + dw * dw, sbuf, tid) * (1.f / 1024.f);
    float r = rsqrtf(var + 1e-6f);
    float4 gv = ((const float4*)g)[tid];
    float4 bv = ((const float4*)b)[tid];
    float4 o;
    o.x = dx * r * gv.x + bv.x; o.y = dy * r * gv.y + bv.y;
    o.z = dz * r * gv.z + bv.z; o.w = dw * r * gv.w + bv.w;
    ((float4*)(dstf + (size_t)t * 1024))[tid] = o;
    if (WB) {
        ushort4 u; u.x = f2bf(o.x); u.y = f2bf(o.y); u.z = f2bf(o.z); u.w = f2bf(o.w);
        ((ushort4*)(dstb + (size_t)t * 1024))[tid] = u;
    }
}

// ---------- launcher ----------
extern "C" void kernel_launch(void* const* d_in, const int* in_sizes, int n_in,
                              void* d_out, int out_size, void* d_ws, size_t ws_size,
                              hipStream_t stream) {
    (void)in_sizes; (void)n_in; (void)out_size; (void)ws_size;
    const float* x    = (const float*)d_in[0];
    const float* Wq   = (const float*)d_in[1];
    const float* Wk   = (const float*)d_in[2];
    const float* Wv   = (const float*)d_in[3];
    const float* Wo   = (const float*)d_in[4];
    const float* proj = (const float*)d_in[5];
    const float* W1   = (const float*)d_in[6];
    const float* b1   = (const float*)d_in[7];
    const float* W2   = (const float*)d_in[8];
    const float* b2   = (const float*)d_in[9];
    const float* g1   = (const float*)d_in[10];
    const float* lb1  = (const float*)d_in[11];
    const float* g2   = (const float*)d_in[12];
    const float* lb2  = (const float*)d_in[13];

    char* ws = (char*)d_ws;
    size_t off = 0;
    auto alloc = [&](size_t bytes) { char* p = ws + off; off += (bytes + 255) & ~(size_t)255; return p; };
    unsigned short* WqkvT = (unsigned short*)alloc((size_t)3072 * 1024 * 2);
    unsigned short* WoT   = (unsigned short*)alloc((size_t)1024 * 1024 * 2);
    unsigned short* W1T   = (unsigned short*)alloc((size_t)4096 * 1024 * 2);
    unsigned short* W2T   = (unsigned short*)alloc((size_t)1024 * 4096 * 2);
    unsigned short* xb    = (unsigned short*)alloc((size_t)16384 * 1024 * 2);  // later: attn
    unsigned short* qkvb  = (unsigned short*)alloc((size_t)16384 * 3072 * 2);  // later: out1f + out1b
    unsigned short* qf    = (unsigned short*)alloc((size_t)16384 * 1024 * 2);  // later: h_half (with vT)
    unsigned short* vT    = (unsigned short*)alloc((size_t)16384 * 1024 * 2);  // [bh][d][n]
    float* kv    = (float*)alloc((size_t)64 * 64 * 64 * 4);
    float* ksum  = (float*)alloc((size_t)64 * 64 * 4);
    float* diagk = (float*)alloc((size_t)16384 * 16 * 4);
    float* bmax  = (float*)alloc((size_t)16384 * 4);
    float* mx    = (float*)alloc(256);

    unsigned short* attnb = xb;
    float* out1f = (float*)qkvb;
    unsigned short* out1b = (unsigned short*)((char*)qkvb + (size_t)16384 * 1024 * 4);
    unsigned short* hhalf = qf;                 // 64 MB: overlays qf+vT
    float* kdash = (float*)d_out;               // d_out doubles as fp32 scratch
    float* preLN = (float*)d_out;

    dim3 tb(32, 8);
    transpose_cvt<<<dim3(32, 32), tb, 0, stream>>>(Wq, WqkvT, 1024, 1024);
    transpose_cvt<<<dim3(32, 32), tb, 0, stream>>>(Wk, WqkvT + 1024 * 1024, 1024, 1024);
    transpose_cvt<<<dim3(32, 32), tb, 0, stream>>>(Wv, WqkvT + 2 * 1024 * 1024, 1024, 1024);
    transpose_cvt<<<dim3(32, 32), tb, 0, stream>>>(Wo, WoT, 1024, 1024);
    transpose_cvt<<<dim3(128, 32), tb, 0, stream>>>(W1, W1T, 1024, 4096);
    transpose_cvt<<<dim3(32, 128), tb, 0, stream>>>(W2, W2T, 4096, 1024);
    cvt_bf16<<<16384, 256, 0, stream>>>((const float4*)x, (ushort4*)xb);

    // QKV: [16384,1024] x [1024,3072]; Q,K -> qkvb (bf16), V -> vT (transposed)
    gemm_bt<EP_QKV><<<dim3(24, 128), 256, 0, stream>>>(xb, 1024, WqkvT, 1024, 1024, 3072,
                                                       nullptr, qkvb, nullptr, nullptr, vT);
    feat_mfma<<<2048, 256, 0, stream>>>(qkvb, proj, qf, kdash, diagk, bmax);
    max_reduce<<<1, 256, 0, stream>>>(bmax, mx);
    hipMemsetAsync(kv, 0, (size_t)64 * 64 * 64 * 4 + (size_t)64 * 64 * 4, stream);
    kv_fused<<<dim3(64, 4), 256, 0, stream>>>(kdash, diagk, mx, vT, kv, ksum);
    attn_mfma<<<dim3(64, 32), 256, 0, stream>>>(qf, kv, ksum, attnb);
    // attn @ Wo + x -> preLN1 (in d_out)
    gemm_bt<EP_ADDF32><<<dim3(8, 128), 256, 0, stream>>>(attnb, 1024, WoT, 1024, 1024, 1024,
                                                         preLN, nullptr, nullptr, x, nullptr);
    ln_kernel<1><<<16384, 256, 0, stream>>>(preLN, g1, lb1, out1f, out1b);
    // FFN in two DFF halves (h_half reused)
    gemm_bt<EP_BIAS_ELU_BF16><<<dim3(16, 128), 256, 0, stream>>>(out1b, 1024, W1T, 1024, 1024, 2048,
                                                                 nullptr, hhalf, b1, nullptr, nullptr);
    gemm_bt<EP_BIAS_ADD_F32><<<dim3(8, 128), 256, 0, stream>>>(hhalf, 2048, W2T, 4096, 2048, 1024,
                                                               preLN, nullptr, b2, out1f, nullptr);
    gemm_bt<EP_BIAS_ELU_BF16><<<dim3(16, 128), 256, 0, stream>>>(out1b, 1024, W1T + (size_t)2048 * 1024,
                                                                 1024, 1024, 2048, nullptr, hhalf,
                                                                 b1 + 2048, nullptr, nullptr);
    gemm_bt<EP_ADDF32><<<dim3(8, 128), 256, 0, stream>>>(hhalf, 2048, W2T + 2048, 4096, 2048, 1024,
                                                         preLN, nullptr, nullptr, preLN, nullptr);
    ln_kernel<0><<<16384, 256, 0, stream>>>(preLN, g2, lb2, (float*)d_out, nullptr);
}

// Round 4
// 885.891 us; speedup vs baseline: 1.6404x; 1.0885x over previous
//
#include <hip/hip_runtime.h>
#include <math.h>

// ---------- types / helpers ----------
typedef __attribute__((ext_vector_type(8))) short s16x8;
typedef __attribute__((ext_vector_type(4))) float f32x4;

__device__ __forceinline__ float bf2f(unsigned short u) {
    union { unsigned int i; float f; } c; c.i = ((unsigned int)u) << 16; return c.f;
}
__device__ __forceinline__ unsigned short f2bf(float f) {
    union { float f; unsigned int i; } c; c.f = f;
    unsigned int r = c.i + 0x7fffu + ((c.i >> 16) & 1u);
    return (unsigned short)(r >> 16);
}
__device__ __forceinline__ float wave_sum(float v) {
#pragma unroll
    for (int o = 32; o; o >>= 1) v += __shfl_xor(v, o, 64);
    return v;
}
__device__ __forceinline__ float wave_max(float v) {
#pragma unroll
    for (int o = 32; o; o >>= 1) v = fmaxf(v, __shfl_xor(v, o, 64));
    return v;
}
__device__ __forceinline__ void async_load16(const void* g, void* l) {
    __builtin_amdgcn_global_load_lds(
        (const __attribute__((address_space(1))) unsigned int*)g,
        (__attribute__((address_space(3))) unsigned int*)l, 16, 0, 0);
}

// ---------- bf16 GEMM: C[M,N] = A[M,K] * BT[N,K]^T, 128x128 tile ----------
enum { EP_BF16 = 0, EP_ADDF32 = 1, EP_BIAS_ELU_BF16 = 2, EP_QKV = 4, EP_BIAS_ADDBF16 = 5 };

template <int EP>
__global__ __launch_bounds__(256, 2) void gemm_bt(
    const unsigned short* __restrict__ A, int lda,
    const unsigned short* __restrict__ BT, int ldb,
    int K, int ldc,
    float* Cf, unsigned short* Cb,
    const float* __restrict__ bias, const float* addsrc,
    const unsigned short* __restrict__ addb,
    unsigned short* vtout)
{
    __shared__ __align__(16) unsigned short sA[128 * 32];
    __shared__ __align__(16) unsigned short sB[128 * 32];
    const int tid = threadIdx.x;
    const int w = tid >> 6, l = tid & 63;
    const int wm = w & 1, wn = w >> 1;
    const int rowBase = blockIdx.y * 128, colBase = blockIdx.x * 128;

    f32x4 acc[4][4] = {};

    const int sr = w * 32 + (l >> 2);
    const int sc = (l & 3) * 8;
    const unsigned short* gA0 = A + (size_t)(rowBase + sr) * lda + sc;
    const unsigned short* gA1 = gA0 + (size_t)16 * lda;
    const unsigned short* gB0 = BT + (size_t)(colBase + sr) * ldb + sc;
    const unsigned short* gB1 = gB0 + (size_t)16 * ldb;
    unsigned short* lA0 = sA + (w * 32) * 32;
    unsigned short* lA1 = sA + (w * 32 + 16) * 32;
    unsigned short* lB0 = sB + (w * 32) * 32;
    unsigned short* lB1 = sB + (w * 32 + 16) * 32;

    const int lm = l & 15, lq = l >> 4;
    const int aoff = (wm * 64 + lm) * 32 + lq * 8;
    const int boff = (wn * 64 + lm) * 32 + lq * 8;

    for (int k0 = 0; k0 < K; k0 += 32) {
        __syncthreads();
        async_load16(gA0 + k0, lA0);
        async_load16(gA1 + k0, lA1);
        async_load16(gB0 + k0, lB0);
        async_load16(gB1 + k0, lB1);
        __syncthreads();
        s16x8 af[4], bfr[4];
#pragma unroll
        for (int mi = 0; mi < 4; ++mi) af[mi] = *(const s16x8*)(sA + aoff + mi * 512);
#pragma unroll
        for (int ni = 0; ni < 4; ++ni) bfr[ni] = *(const s16x8*)(sB + boff + ni * 512);
#pragma unroll
        for (int mi = 0; mi < 4; ++mi)
#pragma unroll
            for (int ni = 0; ni < 4; ++ni)
                acc[mi][ni] = __builtin_amdgcn_mfma_f32_16x16x32_bf16(
                    af[mi], bfr[ni], acc[mi][ni], 0, 0, 0);
    }

    if (EP == EP_QKV && colBase >= 2048) {
        // write V part transposed: vT[(b*16+h)*64+d][n], 4 consecutive tokens -> ushort4
#pragma unroll
        for (int mi = 0; mi < 4; ++mi) {
            const int row0 = rowBase + wm * 64 + mi * 16 + lq * 4;
            const int bb = row0 >> 12, nn = row0 & 4095;
#pragma unroll
            for (int ni = 0; ni < 4; ++ni) {
                const int c = colBase + wn * 64 + ni * 16 + lm - 2048;
                const int hv = c >> 6, dv = c & 63;
                ushort4 u;
                u.x = f2bf(acc[mi][ni][0]); u.y = f2bf(acc[mi][ni][1]);
                u.z = f2bf(acc[mi][ni][2]); u.w = f2bf(acc[mi][ni][3]);
                *(ushort4*)(vtout + ((size_t)(bb * 16 + hv) * 64 + dv) * 4096 + nn) = u;
            }
        }
    } else {
#pragma unroll
        for (int mi = 0; mi < 4; ++mi) {
            const int r0 = rowBase + wm * 64 + mi * 16 + lq * 4;
#pragma unroll
            for (int ni = 0; ni < 4; ++ni) {
                const int c = colBase + wn * 64 + ni * 16 + lm;
                float bv = 0.f;
                if (EP == EP_BIAS_ELU_BF16 || EP == EP_BIAS_ADDBF16) bv = bias[c];
#pragma unroll
                for (int r = 0; r < 4; ++r) {
                    const size_t idx = (size_t)(r0 + r) * ldc + c;
                    float v = acc[mi][ni][r] + bv;
                    if (EP == EP_ADDF32) v += addsrc[idx];
                    if (EP == EP_BIAS_ADDBF16) v += bf2f(addb[idx]);
                    if (EP == EP_BIAS_ELU_BF16) v = v > 0.f ? v : (expf(v) - 1.f);
                    if (EP == EP_BF16 || EP == EP_BIAS_ELU_BF16 || EP == EP_QKV) Cb[idx] = f2bf(v);
                    else Cf[idx] = v;
                }
            }
        }
    }
}

// ---------- all weight transposes + f32->bf16 in one dispatch ----------
__global__ __launch_bounds__(256) void transpose_all(
    const float* __restrict__ Wq, const float* __restrict__ Wk,
    const float* __restrict__ Wv, const float* __restrict__ Wo,
    const float* __restrict__ W1, const float* __restrict__ W2,
    unsigned short* WqkvT, unsigned short* WoT,
    unsigned short* W1T, unsigned short* W2T)
{
    __shared__ float t[32][33];
    const int bid = blockIdx.x;
    const float* in;
    unsigned short* out;
    int R, C, tx32, ty32;
    if (bid < 4096) {
        const int job = bid >> 10, tile = bid & 1023;
        ty32 = tile >> 5; tx32 = tile & 31;
        R = 1024; C = 1024;
        if (job == 0)      { in = Wq; out = WqkvT; }
        else if (job == 1) { in = Wk; out = WqkvT + 1024 * 1024; }
        else if (job == 2) { in = Wv; out = WqkvT + 2 * 1024 * 1024; }
        else               { in = Wo; out = WoT; }
    } else if (bid < 8192) {
        const int tile = bid - 4096;           // W1 [1024,4096]: 128 x-tiles, 32 y-tiles
        tx32 = tile & 127; ty32 = tile >> 7;
        R = 1024; C = 4096; in = W1; out = W1T;
    } else {
        const int tile = bid - 8192;           // W2 [4096,1024]: 32 x-tiles, 128 y-tiles
        tx32 = tile & 31; ty32 = tile >> 5;
        R = 4096; C = 1024; in = W2; out = W2T;
    }
    const int c0 = tx32 * 32, r0 = ty32 * 32;
    const int tx = threadIdx.x, ty = threadIdx.y;
#pragma unroll
    for (int j = 0; j < 4; ++j)
        t[ty + j * 8][tx] = in[(size_t)(r0 + ty + j * 8) * C + c0 + tx];
    __syncthreads();
#pragma unroll
    for (int j = 0; j < 4; ++j) {
        int cc = ty + j * 8;
        out[(size_t)(c0 + cc) * R + r0 + tx] = f2bf(t[tx][cc]);
    }
}

__global__ __launch_bounds__(256) void cvt_bf16(const float4* in, ushort4* out) {
    size_t i = (size_t)blockIdx.x * 256 + threadIdx.x;
    float4 v = in[i];
    ushort4 o; o.x = f2bf(v.x); o.y = f2bf(v.y); o.z = f2bf(v.z); o.w = f2bf(v.w);
    out[i] = o;
}

// ---------- FAVOR+ features via MFMA ----------
__global__ __launch_bounds__(256, 2) void feat_mfma(
    const unsigned short* __restrict__ qkvb, const float* __restrict__ proj,
    unsigned short* __restrict__ qf, float* __restrict__ kdash,
    float* __restrict__ diagk, float* __restrict__ bmax)
{
    __shared__ __align__(16) unsigned short sQ[8192];  // [2 ks][128 rows][32 k]
    __shared__ __align__(16) unsigned short sK[8192];
    __shared__ __align__(16) unsigned short sP[4096];  // proj [2 ks][64 m][32 k]
    __shared__ float sdq[128], sdk[128];
    __shared__ float swm[4];
    const int tid = threadIdx.x, w = tid >> 6, l = tid & 63;
    const int t0 = blockIdx.x * 8;
    const int lm = l & 15, lq = l >> 4;

#pragma unroll
    for (int j = 0; j < 4; ++j) {
        const int lt = 2 * w + (j & 1), ks = j >> 1;
        const size_t g = (size_t)(t0 + lt) * 3072 + (l >> 2) * 64 + ks * 32 + (l & 3) * 8;
        async_load16(qkvb + g, sQ + ks * 4096 + lt * 512);
        async_load16(qkvb + g + 1024, sK + ks * 4096 + lt * 512);
    }
    for (int i = tid; i < 4096; i += 256) {
        int m = i >> 6, d = i & 63;
        sP[(d >> 5) * 2048 + m * 32 + (d & 31)] = f2bf(proj[i]);
    }
    __syncthreads();

    {
        int r = tid & 127;
        const unsigned short* src = (tid < 128) ? sQ : sK;
        float s = 0.f;
#pragma unroll
        for (int ks = 0; ks < 2; ++ks) {
            const s16x8* p = (const s16x8*)(src + ks * 4096 + r * 32);
#pragma unroll
            for (int c = 0; c < 4; ++c) {
                s16x8 v = p[c];
#pragma unroll
                for (int e = 0; e < 8; ++e) { float f = bf2f((unsigned short)v[e]); s += f * f; }
            }
        }
        if (tid < 128) sdq[r] = s * 0.0625f; else sdk[r] = s * 0.0625f;
    }
    __syncthreads();

    s16x8 pf2[2][4];
#pragma unroll
    for (int ks = 0; ks < 2; ++ks)
#pragma unroll
        for (int ni = 0; ni < 4; ++ni)
            pf2[ks][ni] = *(const s16x8*)(sP + ks * 2048 + (ni * 16 + lm) * 32 + lq * 8);
    f32x4 qa[2][4] = {}, ka[2][4] = {};
#pragma unroll
    for (int i = 0; i < 2; ++i) {
        const int rowt = (w * 2 + i) * 16 + lm;
#pragma unroll
        for (int ks = 0; ks < 2; ++ks) {
            s16x8 aq = *(const s16x8*)(sQ + ks * 4096 + rowt * 32 + lq * 8);
            s16x8 ak = *(const s16x8*)(sK + ks * 4096 + rowt * 32 + lq * 8);
#pragma unroll
            for (int ni = 0; ni < 4; ++ni) {
                qa[i][ni] = __builtin_amdgcn_mfma_f32_16x16x32_bf16(aq, pf2[ks][ni], qa[i][ni], 0, 0, 0);
                ka[i][ni] = __builtin_amdgcn_mfma_f32_16x16x32_bf16(ak, pf2[ks][ni], ka[i][ni], 0, 0, 0);
            }
        }
    }

    const float dn = 0.35355339059327373f;
    float kmax = -3.0e38f;
#pragma unroll
    for (int i = 0; i < 2; ++i) {
#pragma unroll
        for (int r = 0; r < 4; ++r) {
            const int row = (w * 2 + i) * 16 + lq * 4 + r;
            float q0 = qa[i][0][r] * dn, q1 = qa[i][1][r] * dn;
            float q2 = qa[i][2][r] * dn, q3 = qa[i][3][r] * dn;
            float mq = fmaxf(fmaxf(q0, q1), fmaxf(q2, q3));
#pragma unroll
            for (int o = 1; o < 16; o <<= 1) mq = fmaxf(mq, __shfl_xor(mq, o, 64));
            const float dg = sdq[row];
            const size_t ob = (size_t)t0 * 1024 + (size_t)row * 64 + lm;
            qf[ob]      = f2bf(0.125f * (expf(q0 - dg - mq) + 1e-6f));
            qf[ob + 16] = f2bf(0.125f * (expf(q1 - dg - mq) + 1e-6f));
            qf[ob + 32] = f2bf(0.125f * (expf(q2 - dg - mq) + 1e-6f));
            qf[ob + 48] = f2bf(0.125f * (expf(q3 - dg - mq) + 1e-6f));
#pragma unroll
            for (int ni = 0; ni < 4; ++ni) {
                float kd = ka[i][ni][r] * dn;
                kdash[ob + ni * 16] = kd;
                kmax = fmaxf(kmax, kd);
            }
        }
    }
    kmax = wave_max(kmax);
    if (l == 0) swm[w] = kmax;
    __syncthreads();
    if (tid < 128) diagk[t0 * 16 + tid] = sdk[tid];
    if (tid == 0) bmax[blockIdx.x] = fmaxf(fmaxf(swm[0], swm[1]), fmaxf(swm[2], swm[3]));
}

__global__ __launch_bounds__(256) void max_reduce(const float* bm, float* mx) {
    const int tid = threadIdx.x;
    float m = -3.0e38f;
    for (int i = tid; i < 2048; i += 256) m = fmaxf(m, bm[i]);
    m = wave_max(m);
    __shared__ float s[4];
    if ((tid & 63) == 0) s[tid >> 6] = m;
    __syncthreads();
    if (tid == 0) mx[0] = fmaxf(fmaxf(s[0], s[1]), fmaxf(s[2], s[3]));
}

// ---------- fused kf + kv/ksum via MFMA ----------
__global__ __launch_bounds__(256, 2) void kv_fused(
    const float* __restrict__ kdash, const float* __restrict__ diagk,
    const float* __restrict__ mx, const unsigned short* __restrict__ vT,
    float* kv, float* ksum)
{
    __shared__ __align__(16) unsigned short sKF[64 * 72];
    __shared__ __align__(16) unsigned short sV[64 * 72];
    __shared__ float sDiag[1024];
    const int tid = threadIdx.x, w = tid >> 6, l = tid & 63;
    const int bh = blockIdx.x, b = bh >> 4, h = bh & 15;
    const int n0 = blockIdx.y * 1024;
    const int lm = l & 15, lq = l >> 4;
    const float mxv = mx[0];

    for (int i = tid; i < 1024; i += 256)
        sDiag[i] = diagk[(size_t)(b * 4096 + n0 + i) * 16 + h] + mxv;

    s16x8 onesf;
    {
        short ov = (lm == 0) ? (short)0x3F80 : (short)0;
#pragma unroll
        for (int j = 0; j < 8; ++j) onesf[j] = ov;
    }
    f32x4 acc[4] = {};
    f32x4 accS = {};
    __syncthreads();

    for (int c0 = 0; c0 < 1024; c0 += 64) {
        __syncthreads();
        {
            const int n = c0 + l;
            const size_t krow = ((size_t)(b * 4096 + n0 + n)) * 1024 + h * 64 + w * 16;
            const float4* kp = (const float4*)(kdash + krow);
            float4 k0 = kp[0], k1 = kp[1], k2 = kp[2], k3 = kp[3];
            const float dg = sDiag[n];
            float vv[16] = {k0.x, k0.y, k0.z, k0.w, k1.x, k1.y, k1.z, k1.w,
                            k2.x, k2.y, k2.z, k2.w, k3.x, k3.y, k3.z, k3.w};
            unsigned short* dst = sKF + (w * 16) * 72 + l;
#pragma unroll
            for (int e = 0; e < 16; ++e)
                dst[e * 72] = f2bf(0.125f * (expf(vv[e] - dg) + 1e-6f));
        }
        {
            const int d = tid >> 2, nq = tid & 3;
            const uint4* vp = (const uint4*)(vT + ((size_t)bh * 64 + d) * 4096 + n0 + c0 + nq * 16);
            uint4 v0 = vp[0], v1 = vp[1];
            uint4* ldst = (uint4*)(sV + d * 72 + nq * 16);
            ldst[0] = v0; ldst[1] = v1;
        }
        __syncthreads();
#pragma unroll
        for (int ks = 0; ks < 2; ++ks) {
            s16x8 a = *(const s16x8*)(sKF + (w * 16 + lm) * 72 + ks * 32 + lq * 8);
            accS = __builtin_amdgcn_mfma_f32_16x16x32_bf16(a, onesf, accS, 0, 0, 0);
#pragma unroll
            for (int ni = 0; ni < 4; ++ni) {
                s16x8 bf = *(const s16x8*)(sV + (ni * 16 + lm) * 72 + ks * 32 + lq * 8);
                acc[ni] = __builtin_amdgcn_mfma_f32_16x16x32_bf16(a, bf, acc[ni], 0, 0, 0);
            }
        }
    }

    const size_t kvbase = (size_t)bh * 4096;
#pragma unroll
    for (int ni = 0; ni < 4; ++ni)
#pragma unroll
        for (int r = 0; r < 4; ++r)
            atomicAdd(kv + kvbase + (size_t)(w * 16 + lq * 4 + r) * 64 + ni * 16 + lm, acc[ni][r]);
    if (lm == 0)
#pragma unroll
        for (int r = 0; r < 4; ++r)
            atomicAdd(ksum + bh * 64 + w * 16 + lq * 4 + r, accS[r]);
}

// ---------- attention combine via MFMA, den folded as output column 64 ----------
__global__ __launch_bounds__(256, 2) void attn_mfma(const unsigned short* __restrict__ qf,
                                                    const float* __restrict__ kv,
                                                    const float* __restrict__ ksum,
                                                    unsigned short* __restrict__ attn) {
    __shared__ __align__(16) unsigned short sA[8192];  // [2 ks][128 rows][32 m]
    __shared__ __align__(16) unsigned short sB[5120];  // [2 ks][80 cols][32 m]; col64=ksum
    const int tid = threadIdx.x, w = tid >> 6, l = tid & 63;
    const int bh = blockIdx.x, b = bh >> 4, h = bh & 15;
    const int n0 = blockIdx.y * 128;
    const int lm = l & 15, lq = l >> 4;

#pragma unroll
    for (int j = 0; j < 4; ++j) {
        const int r0 = w * 32 + (j & 1) * 16, ks = j >> 1;
        const size_t g = (size_t)(b * 4096 + n0 + r0 + (l >> 2)) * 1024 + h * 64 + ks * 32 + (l & 3) * 8;
        async_load16(qf + g, sA + ks * 4096 + r0 * 32);
    }
    for (int i = tid; i < 5120; i += 256) sB[i] = 0;
    __syncthreads();
    for (int i = tid; i < 4096; i += 256) {
        int m = i >> 6, d = i & 63;
        sB[(m >> 5) * 2560 + d * 32 + (m & 31)] = f2bf(kv[(size_t)bh * 4096 + i]);
    }
    if (tid < 64) {
        int m = tid;
        sB[(m >> 5) * 2560 + 64 * 32 + (m & 31)] = f2bf(ksum[bh * 64 + m]);
    }
    __syncthreads();

    s16x8 bf2r[2][5];
#pragma unroll
    for (int ks = 0; ks < 2; ++ks)
#pragma unroll
        for (int ni = 0; ni < 5; ++ni)
            bf2r[ks][ni] = *(const s16x8*)(sB + ks * 2560 + (ni * 16 + lm) * 32 + lq * 8);
    f32x4 acc[2][5] = {};
#pragma unroll
    for (int i = 0; i < 2; ++i) {
        const int rowt = (w * 2 + i) * 16 + lm;
#pragma unroll
        for (int ks = 0; ks < 2; ++ks) {
            s16x8 a = *(const s16x8*)(sA + ks * 4096 + rowt * 32 + lq * 8);
#pragma unroll
            for (int ni = 0; ni < 5; ++ni)
                acc[i][ni] = __builtin_amdgcn_mfma_f32_16x16x32_bf16(a, bf2r[ks][ni], acc[i][ni], 0, 0, 0);
        }
    }
#pragma unroll
    for (int i = 0; i < 2; ++i) {
#pragma unroll
        for (int r = 0; r < 4; ++r) {
            const int row = (w * 2 + i) * 16 + lq * 4 + r;
            float den = __shfl(acc[i][4][r], l & 48, 64);
            float rd = 1.f / den;
            const size_t ob = (size_t)(b * 4096 + n0 + row) * 1024 + h * 64 + lm;
            attn[ob]      = f2bf(acc[i][0][r] * rd);
            attn[ob + 16] = f2bf(acc[i][1][r] * rd);
            attn[ob + 32] = f2bf(acc[i][2][r] * rd);
            attn[ob + 48] = f2bf(acc[i][3][r] * rd);
        }
    }
}

// ---------- LayerNorm (D=1024) ----------
__device__ __forceinline__ float block_sum256(float v, float* sbuf, int tid) {
    v = wave_sum(v);
    __syncthreads();
    if ((tid & 63) == 0) sbuf[tid >> 6] = v;
    __syncthreads();
    return sbuf[0] + sbuf[1] + sbuf[2] + sbuf[3];
}

template <int WF32, int WBF16>
__global__ __launch_bounds__(256) void ln_kernel(const float* src, const float* g, const float* b,
                                                 float* dstf, unsigned short* dstb) {
    __shared__ float sbuf[4];
    const int t = blockIdx.x, tid = threadIdx.x;
    float4 v = ((const float4*)(src + (size_t)t * 1024))[tid];
    float mu = block_sum256(v.x + v.y + v.z + v.w, sbuf, tid) * (1.f / 1024.f);
    float dx = v.x - mu, dy = v.y - mu, dz = v.z - mu, dw = v.w - mu;
    float var = block_sum256(dx * dx + dy * dy + dz * dz + dw * dw, sbuf, tid) * (1.f / 1024.f);
    float r = rsqrtf(var + 1e-6f);
    float4 gv = ((const float4*)g)[tid];
    float4 bv = ((const float4*)b)[tid];
    float4 o;
    o.x = dx * r * gv.x + bv.x; o.y = dy * r * gv.y + bv.y;
    o.z = dz * r * gv.z + bv.z; o.w = dw * r * gv.w + bv.w;
    if (WF32) ((float4*)(dstf + (size_t)t * 1024))[tid] = o;
    if (WBF16) {
        ushort4 u; u.x = f2bf(o.x); u.y = f2bf(o.y); u.z = f2bf(o.z); u.w = f2bf(o.w);
        ((ushort4*)(dstb + (size_t)t * 1024))[tid] = u;
    }
}

// ---------- launcher ----------
extern "C" void kernel_launch(void* const* d_in, const int* in_sizes, int n_in,
                              void* d_out, int out_size, void* d_ws, size_t ws_size,
                              hipStream_t stream) {
    (void)in_sizes; (void)n_in; (void)out_size; (void)ws_size;
    const float* x    = (const float*)d_in[0];
    const float* Wq   = (const float*)d_in[1];
    const float* Wk   = (const float*)d_in[2];
    const float* Wv   = (const float*)d_in[3];
    const float* Wo   = (const float*)d_in[4];
    const float* proj = (const float*)d_in[5];
    const float* W1   = (const float*)d_in[6];
    const float* b1   = (const float*)d_in[7];
    const float* W2   = (const float*)d_in[8];
    const float* b2   = (const float*)d_in[9];
    const float* g1   = (const float*)d_in[10];
    const float* lb1  = (const float*)d_in[11];
    const float* g2   = (const float*)d_in[12];
    const float* lb2  = (const float*)d_in[13];

    char* ws = (char*)d_ws;
    size_t off = 0;
    auto alloc = [&](size_t bytes) { char* p = ws + off; off += (bytes + 255) & ~(size_t)255; return p; };
    unsigned short* WqkvT = (unsigned short*)alloc((size_t)3072 * 1024 * 2);
    unsigned short* WoT   = (unsigned short*)alloc((size_t)1024 * 1024 * 2);
    unsigned short* W1T   = (unsigned short*)alloc((size_t)4096 * 1024 * 2);
    unsigned short* W2T   = (unsigned short*)alloc((size_t)1024 * 4096 * 2);
    unsigned short* xb    = (unsigned short*)alloc((size_t)16384 * 1024 * 2);  // later: attn
    unsigned short* qkvb  = (unsigned short*)alloc((size_t)16384 * 3072 * 2);  // later: out1b + h(lo)
    unsigned short* qf    = (unsigned short*)alloc((size_t)16384 * 1024 * 2);  // later: h(mid)
    unsigned short* vT    = (unsigned short*)alloc((size_t)16384 * 1024 * 2);  // later: h(hi)
    float* kv    = (float*)alloc((size_t)64 * 64 * 64 * 4);
    float* ksum  = (float*)alloc((size_t)64 * 64 * 4);
    float* diagk = (float*)alloc((size_t)16384 * 16 * 4);
    float* bmax  = (float*)alloc((size_t)16384 * 4);
    float* mx    = (float*)alloc(256);

    unsigned short* attnb = xb;
    unsigned short* out1b = qkvb;                                   // 32 MB
    unsigned short* h     = qkvb + (size_t)16384 * 1024;            // 128 MB (qkvb hi + qf + vT)
    float* kdash = (float*)d_out;               // d_out doubles as fp32 scratch
    float* preLN = (float*)d_out;

    transpose_all<<<12288, dim3(32, 8), 0, stream>>>(Wq, Wk, Wv, Wo, W1, W2,
                                                     WqkvT, WoT, W1T, W2T);
    cvt_bf16<<<16384, 256, 0, stream>>>((const float4*)x, (ushort4*)xb);

    // QKV: [16384,1024] x [1024,3072]; Q,K -> qkvb (bf16), V -> vT (transposed)
    gemm_bt<EP_QKV><<<dim3(24, 128), 256, 0, stream>>>(xb, 1024, WqkvT, 1024, 1024, 3072,
                                                       nullptr, qkvb, nullptr, nullptr, nullptr, vT);
    feat_mfma<<<2048, 256, 0, stream>>>(qkvb, proj, qf, kdash, diagk, bmax);
    max_reduce<<<1, 256, 0, stream>>>(bmax, mx);
    hipMemsetAsync(kv, 0, (size_t)64 * 64 * 64 * 4 + (size_t)64 * 64 * 4, stream);
    kv_fused<<<dim3(64, 4), 256, 0, stream>>>(kdash, diagk, mx, vT, kv, ksum);
    attn_mfma<<<dim3(64, 32), 256, 0, stream>>>(qf, kv, ksum, attnb);
    // attn @ Wo + x -> preLN1 (in d_out)
    gemm_bt<EP_ADDF32><<<dim3(8, 128), 256, 0, stream>>>(attnb, 1024, WoT, 1024, 1024, 1024,
                                                         preLN, nullptr, nullptr, x, nullptr, nullptr);
    ln_kernel<0, 1><<<16384, 256, 0, stream>>>(preLN, g1, lb1, nullptr, out1b);
    // FFN full-DFF: h = elu(out1b @ W1 + b1)  [16384,4096]
    gemm_bt<EP_BIAS_ELU_BF16><<<dim3(32, 128), 256, 0, stream>>>(out1b, 1024, W1T, 1024, 1024, 4096,
                                                                 nullptr, h, b1, nullptr, nullptr, nullptr);
    // preLN2 = h @ W2 + b2 + out1  (K=4096)
    gemm_bt<EP_BIAS_ADDBF16><<<dim3(8, 128), 256, 0, stream>>>(h, 4096, W2T, 4096, 4096, 1024,
                                                               preLN, nullptr, b2, nullptr, out1b, nullptr);
    ln_kernel<1, 0><<<16384, 256, 0, stream>>>(preLN, g2, lb2, (float*)d_out, nullptr);
}